// Round 11
// baseline (461.228 us; speedup 1.0000x reference)
//
#include <hip/hip_runtime.h>
#include <stdint.h>

// ---------------------------------------------------------------------------
// RPN loss: IoU>0.7 matching + argmax fix + exact JAX threefry sampling
// (partitionable PRNG path) + smooth-L1 + BCE, all on device.
// R1-R7: algorithmic fixes (2785 -> 314us). R8-R10: launch collapse (385).
// R10 analysis: hist3's cost was 12.6M GLOBAL ATOMIC flushes (512 blk x 8192
// bins x 3 rounds, +50MB dirty lines), not threefry. R9 lookback theory was
// wrong (flat). R11:
//  - k_big: hist via packed-u16 LDS + PLAIN per-block slice stores
//    (hist3Blk, 0 global atomics) + 48-block in-kernel reduce (done-counter
//    spin; grid=256 => 1 blk/CU co-resident) + scanloc0 + pos chain. 
//  - threefry rotates via __builtin_amdgcn_alignbit (1 op vs 3).
//  - launches 13 -> 11.
// ---------------------------------------------------------------------------

#define N_PRED   131072
#define NBOXK    64
#define NM_TOT   8388608u          // N_PRED * NBOXK
#define TCAP     65536
#define NBINS    8192
#define BINSHIFT 19                // key >> 19 -> 13-bit bin
#define SLOTCAP  3072
#define MAXSLOT  192
#define HCAP     2048              // per-block LDS hit buffer (gather)
#define CBLK     512               // iou/scan blocks
#define POSCAP   32                // per-bin candidate cap in k_pos
#define HWORK    255               // hist worker blocks in k_big
#define HRED     48                // reducer blocks in k_big

typedef unsigned long long ull;

struct WS {
  // ---- zeroed by hipMemsetAsync at the head of every launch ----
  uint32_t iouDone, histDone, redDone, selDone[2], zpad[3];   // 32B
  ull      lookback[CBLK];                                    // 4KB
  // ---- end zero region (ZBYTES) ----
  uint32_t P, M, n_pos, n_neg;
  uint32_t R[2], S[2], kcnt[2];
  uint32_t sub[2][3][2];            // per-round subkeys
  uint32_t nslots;
  uint32_t hist3[3][NBINS];         // reduced hists (plain-written)
  ull      colBestBlk[CBLK][NBOXK]; // per-block iou argmax partials
  ull      maskWords[N_PRED];
  uint32_t T[TCAP];
  uint32_t tgt[2][256];
  int32_t  binslot[NBINS];
  int32_t  tslot[256];
  uint32_t tlocal[256];
  uint32_t slotCnt[MAXSLOT];
  ull      slotBuf[MAXSLOT][SLOTCAP];
  uint32_t hist3Blk[3][256][4096];  // per-block u16-pair hist slices, 12.6MB
  uint16_t binid3[3][NM_TOT];       // 50MB bin-id cache (ws is 256MB)
};
#define ZBYTES (32 + CBLK*8)

// rotate-left via v_alignbit_b32 (single VALU op)
__device__ __forceinline__ uint32_t rotl(uint32_t x, uint32_t r) {
  return __builtin_amdgcn_alignbit(x, x, 32u - r);
}

// Threefry-2x32-20, matches JAX reference implementation exactly.
__device__ __forceinline__ void tf2(uint32_t k0, uint32_t k1,
                                    uint32_t& x0, uint32_t& x1) {
  uint32_t k2 = k0 ^ k1 ^ 0x1BD11BDAu;
  x0 += k0; x1 += k1;
#define QR(r) { x0 += x1; x1 = rotl(x1, r); x1 ^= x0; }
  QR(13) QR(15) QR(26) QR(6)  x0 += k1; x1 += k2 + 1u;
  QR(17) QR(29) QR(16) QR(24) x0 += k2; x1 += k0 + 2u;
  QR(13) QR(15) QR(26) QR(6)  x0 += k0; x1 += k1 + 3u;
  QR(17) QR(29) QR(16) QR(24) x0 += k1; x1 += k2 + 4u;
  QR(13) QR(15) QR(26) QR(6)  x0 += k2; x1 += k0 + 5u;
#undef QR
}

__device__ __forceinline__ uint32_t tf_bits(uint32_t k0, uint32_t k1, uint32_t p) {
  uint32_t a = 0u, b = p;
  tf2(k0, k1, a, b);
  return a ^ b;
}

__device__ __forceinline__ ull umax64(ull a, ull b) { return a > b ? a : b; }

// IoU mask + per-column argmax; per-block partials; last block reduces and
// applies the "need" fixup. Lane l owns column l (zero shuffles).
__global__ __launch_bounds__(256) void k_iou(const float4* __restrict__ pred,
                                             const float4* __restrict__ tgtb,
                                             WS* ws) {
  __shared__ float4 sp[256];
  __shared__ ull cb[NBOXK];
  __shared__ ull red[4][NBOXK];
  __shared__ uint32_t lastF;
  int t = threadIdx.x;
  int lane = t & 63;
  int w = t >> 6;
  int rowBase = blockIdx.x * 256;
  sp[t] = pred[rowBase + t];
  if (t < NBOXK) cb[t] = 0ull;
  float4 tb = tgtb[lane];
  float ta = __fmul_rn(__fsub_rn(tb.z, tb.x), __fsub_rn(tb.w, tb.y));
  __syncthreads();
  ull myWord = 0ull;
  float bestI = -1.0f;
  uint32_t bestRow = 0u;
  int wbase = w * 64;
  for (int r = 0; r < 64; ++r) {
    float4 p = sp[wbase + r];
    float pa = __fmul_rn(__fsub_rn(p.z, p.x), __fsub_rn(p.w, p.y));
    float ltx = fmaxf(p.x, tb.x), lty = fmaxf(p.y, tb.y);
    float rbx = fminf(p.z, tb.z), rby = fminf(p.w, tb.w);
    float wx = fmaxf(__fsub_rn(rbx, ltx), 0.0f);
    float wy = fmaxf(__fsub_rn(rby, lty), 0.0f);
    float inter = __fmul_rn(wx, wy);
    float uni = __fsub_rn(__fadd_rn(pa, ta), inter);
    float iou = __fdiv_rn(inter, uni);
    ull bal = __ballot(iou > 0.7f);
    if (lane == r) myWord = bal;
    if (iou > bestI) { bestI = iou; bestRow = (uint32_t)(rowBase + wbase + r); }
  }
  ws->maskWords[rowBase + wbase + lane] = myWord;
  ull pk = ((ull)__float_as_uint(bestI) << 32) | (ull)(~bestRow);
  atomicMax(&cb[lane], pk);
  __syncthreads();
  if (t < NBOXK) ws->colBestBlk[blockIdx.x][t] = cb[t];
  __threadfence();
  if (t == 0)
    lastF = (atomicAdd(&ws->iouDone, 1u) == (uint32_t)(gridDim.x - 1)) ? 1u : 0u;
  __syncthreads();
  if (lastF) {
    __threadfence();
    int c = t & 63, q = t >> 6;
    ull best = 0ull;
    for (int b = q; b < CBLK; b += 4) best = umax64(best, ws->colBestBlk[b][c]);
    red[q][c] = best;
    __syncthreads();
    if (t < NBOXK) {
      ull m_ = umax64(umax64(red[0][t], red[1][t]), umax64(red[2][t], red[3][t]));
      float bi = __uint_as_float((uint32_t)(m_ >> 32));
      if (!(bi > 0.7f)) {
        uint32_t row = ~(uint32_t)(m_ & 0xFFFFFFFFu);
        atomicOr(&ws->maskWords[row], 1ull << t);
      }
    }
  }
}

// Fused count + global scan (windowed wave-parallel lookback) + ordered emit;
// block 511 does the scalar/PRNG setup.
__global__ __launch_bounds__(256) void k_scan_emit(WS* ws) {
  __shared__ uint32_t sm[256];
  __shared__ uint32_t exclS;
  int t = threadIdx.x, b = blockIdx.x;
  int row = b * 256 + t;
  ull w = ws->maskWords[row];
  uint32_t c = (uint32_t)__popcll(w);
  sm[t] = c;
  __syncthreads();
  for (int off = 1; off < 256; off <<= 1) {
    uint32_t add = (t >= off) ? sm[t - off] : 0u;
    __syncthreads();
    sm[t] += add;
    __syncthreads();
  }
  uint32_t mySum = sm[255];
  if (t == 0) {
    if (b == 0) {
      atomicExch(&ws->lookback[0], (2ull << 32) | (ull)mySum);
      exclS = 0u;
    } else {
      atomicExch(&ws->lookback[b], (1ull << 32) | (ull)mySum);
    }
    __threadfence();
  }
  if (b > 0 && t < 64) {
    int i = b - 1;
    uint32_t run = 0u;
    while (true) {
      int idx = i - t;
      ull x = (idx >= 0) ? atomicAdd(&ws->lookback[idx], 0ull) : (2ull << 32);
      uint32_t st = (uint32_t)(x >> 32);
      ull b2 = __ballot(st == 2u);
      ull b0 = __ballot(st == 0u);
      int f2 = (b2 == 0ull) ? 64 : (__ffsll((long long)b2) - 1);
      int f0 = (b0 == 0ull) ? 64 : (__ffsll((long long)b0) - 1);
      if (f0 < f2) continue;
      uint32_t v = (t <= f2) ? (uint32_t)x : 0u;
#pragma unroll
      for (int o = 32; o > 0; o >>= 1) v += __shfl_xor(v, o, 64);
      run += v;
      if (f2 < 64) break;
      i -= 64;
    }
    if (t == 0) {
      atomicExch(&ws->lookback[b], (2ull << 32) | (ull)(run + mySum));
      exclS = run;
    }
  }
  __syncthreads();
  uint32_t off0 = exclS + sm[t] - c;
  while (w) {
    int bit = __ffsll((long long)w) - 1;
    w &= (w - 1);
    if (off0 < TCAP) ws->T[off0] = ((uint32_t)row << 6) | (uint32_t)bit;
    off0++;
  }
  if (b == CBLK - 1) {
    ws->tgt[0][t] = (uint32_t)t;
    ws->tgt[1][t] = (uint32_t)t;
    if (t == 0) {
      uint32_t total = exclS + mySum;
      uint32_t P = total < (uint32_t)TCAP ? total : (uint32_t)TCAP;
      uint32_t M = NM_TOT - P;
      uint32_t npos = P < 128u ? P : 128u;
      ws->P = P; ws->M = M;
      ws->n_pos = npos; ws->n_neg = 256u - npos;
      ws->S[0] = P; ws->S[1] = M;
      ws->kcnt[0] = npos; ws->kcnt[1] = 256u - npos;
      const double LOGU = 22.18070977791825;  // log(2^32 - 1)
      for (int d = 0; d < 2; ++d) {
        uint32_t Sd = ws->S[d];
        int R = 0;
        if (Sd > 1u) {
          R = (int)ceil(3.0 * log((double)Sd) / LOGU);
          if (R < 1) R = 1;
          if (R > 3) R = 3;
        }
        ws->R[d] = (uint32_t)R;
        uint32_t ck0, ck1;
        { uint32_t a = 0u, bb = (uint32_t)d; tf2(0u, 42u, a, bb); ck0 = a; ck1 = bb; }
        for (int rr = 0; rr < 3; ++rr) {
          uint32_t s0 = 0u, s1 = 1u; tf2(ck0, ck1, s0, s1);
          ws->sub[d][rr][0] = s0; ws->sub[d][rr][1] = s1;
          uint32_t n0 = 0u, n1 = 0u; tf2(ck0, ck1, n0, n1);
          ck0 = n0; ck1 = n1;
        }
      }
    }
  }
}

// scanloc body (1024 threads): LDS scan of hist3[m], per-target binary
// search, LDS bin dedup; writes binslot map + zeroes slotCnt/nslots.
__device__ void scanloc_body(WS* ws, int m, uint32_t* cumS, uint32_t* part,
                             int32_t* bslL, uint32_t* nslL) {
  int t = threadIdx.x;
  const int E = NBINS / 1024;
  uint32_t lv[E];
  uint32_t s = 0;
  uint32_t base = (uint32_t)t * E;
#pragma unroll
  for (int e = 0; e < E; ++e) { lv[e] = ws->hist3[m][base + e]; s += lv[e]; }
  part[t] = s;
  for (int i = t; i < NBINS; i += 1024) bslL[i] = -1;
  if (t == 0) *nslL = 0u;
  __syncthreads();
  for (int off = 1; off < 1024; off <<= 1) {
    uint32_t add = (t >= off) ? part[t - off] : 0u;
    __syncthreads();
    part[t] += add;
    __syncthreads();
  }
  uint32_t run = part[t] - s;
#pragma unroll
  for (int e = 0; e < E; ++e) { cumS[base + e] = run; run += lv[e]; }
  if (t == 1023) cumS[NBINS] = run;
  __syncthreads();
  uint32_t k = ws->kcnt[1];
  uint32_t lo = 0; int old = 0;
  if (t < (int)k) {
    uint32_t tr = ws->tgt[1][t];
    uint32_t hi = NBINS;
    while (hi - lo > 1u) {
      uint32_t mid = (lo + hi) >> 1;
      if (cumS[mid] <= tr) lo = mid; else hi = mid;
    }
    ws->tlocal[t] = tr - cumS[lo];
    old = atomicCAS(&bslL[lo], -1, (int)(0x10000u + (uint32_t)t));
  }
  __syncthreads();
  if (t < (int)k && old == -1) {
    uint32_t sl = atomicAdd(nslL, 1u);
    bslL[lo] = (int)sl;
  }
  __syncthreads();
  if (t < (int)k) ws->tslot[t] = (uint32_t)bslL[lo];
  for (int i = t; i < NBINS; i += 1024) ws->binslot[i] = bslL[i];
  if (t < MAXSLOT) ws->slotCnt[t] = 0u;
  if (t == 0) ws->nslots = *nslL;
}

union SharedU {
  struct { uint32_t lh32[4096]; } hist;                               // 16KB
  struct { uint32_t cumS[NBINS + 1]; uint32_t part[1024];
           int32_t bsl[NBINS]; uint32_t nsl; } scan;                  // 68KB
  struct { uint32_t h8[NBINS]; uint32_t part[1024]; int32_t bsl[NBINS];
           ull sbuf[128][POSCAP]; uint32_t scntL[128];
           uint32_t tg[256], tlo[256], tsl[256]; uint32_t nsl; } pos; // 104KB
};

// k_big: blocks 0..254 compute all 3 neg hists (packed u16-pair LDS, plain
// slice flush -> hist3Blk, NO global atomics) + binid caches; blocks 0..47
// then reduce hist3Blk -> hist3 (4 threads/column, shfl combine); block 0
// finally runs scanloc round 0. Block 255 runs the whole pos chain
// concurrently. grid=256 => 1 block/CU => co-residency guaranteed (spin-safe).
__global__ __launch_bounds__(1024, 4) void k_big(WS* ws) {
  __shared__ SharedU su;
  int b = blockIdx.x, t = threadIdx.x;

  if (b == 255) {
    // ---------------- pos chain ----------------
    int R = (int)ws->R[0];
    uint32_t P = ws->P;
    uint32_t k = ws->kcnt[0];
    if (R < 1) return;
    if (t < 256) su.pos.tg[t] = (uint32_t)t;
    __syncthreads();
    for (int r = R; r >= 1; --r) {
      uint32_t sk0 = ws->sub[0][r - 1][0], sk1 = ws->sub[0][r - 1][1];
      for (int i = t; i < NBINS; i += 1024) su.pos.h8[i] = 0u;
      __syncthreads();
      for (uint32_t j = t; j < P; j += 1024)
        atomicAdd(&su.pos.h8[tf_bits(sk0, sk1, j) >> BINSHIFT], 1u);
      __syncthreads();
      uint32_t lv[NBINS / 1024];
      uint32_t s = 0;
      uint32_t base = (uint32_t)t * (NBINS / 1024);
#pragma unroll
      for (int e = 0; e < NBINS / 1024; ++e) { lv[e] = su.pos.h8[base + e]; s += lv[e]; }
      su.pos.part[t] = s;
      __syncthreads();
      for (int off = 1; off < 1024; off <<= 1) {
        uint32_t add = (t >= off) ? su.pos.part[t - off] : 0u;
        __syncthreads();
        su.pos.part[t] += add;
        __syncthreads();
      }
      uint32_t run = su.pos.part[t] - s;
#pragma unroll
      for (int e = 0; e < NBINS / 1024; ++e) { su.pos.h8[base + e] = run; run += lv[e]; }
      for (int i = t; i < NBINS; i += 1024) su.pos.bsl[i] = -1;
      if (t == 0) su.pos.nsl = 0u;
      if (t < 128) su.pos.scntL[t] = 0u;
      __syncthreads();
      uint32_t lo = 0; int old = 0;
      if (t < (int)k) {
        uint32_t tr = su.pos.tg[t];
        uint32_t hi = NBINS;
        while (hi - lo > 1u) {
          uint32_t mid = (lo + hi) >> 1;
          if (su.pos.h8[mid] <= tr) lo = mid; else hi = mid;
        }
        su.pos.tlo[t] = tr - su.pos.h8[lo];
        old = atomicCAS(&su.pos.bsl[lo], -1, (int)(0x10000u + (uint32_t)t));
      }
      __syncthreads();
      if (t < (int)k && old == -1) {
        uint32_t sl = atomicAdd(&su.pos.nsl, 1u);
        su.pos.bsl[lo] = (int)sl;
      }
      __syncthreads();
      if (t < (int)k) su.pos.tsl[t] = (uint32_t)su.pos.bsl[lo];
      __syncthreads();
      for (uint32_t j = t; j < P; j += 1024) {
        uint32_t kk = tf_bits(sk0, sk1, j);
        int sl = su.pos.bsl[kk >> BINSHIFT];
        if (sl >= 0) {
          uint32_t idx = atomicAdd(&su.pos.scntL[sl], 1u);
          if (idx < POSCAP) su.pos.sbuf[sl][idx] = ((ull)kk << 24) | (ull)j;
        }
      }
      __syncthreads();
      if (t < (int)k) {
        uint32_t sl = su.pos.tsl[t], r2 = su.pos.tlo[t];
        uint32_t cn = su.pos.scntL[sl] < POSCAP ? su.pos.scntL[sl] : POSCAP;
        for (uint32_t x = 0; x < cn; ++x) {
          ull vx = su.pos.sbuf[sl][x];
          uint32_t rank = 0;
          for (uint32_t y = 0; y < cn; ++y) rank += (su.pos.sbuf[sl][y] < vx) ? 1u : 0u;
          if (rank == r2) { su.pos.tg[t] = (uint32_t)(vx & 0xFFFFFFull); break; }
        }
      }
      __syncthreads();
    }
    if (t < (int)k) ws->tgt[0][t] = su.pos.tg[t];
    return;
  }

  // ---------------- hist workers (blocks 0..254) ----------------
  const uint32_t M = ws->M;
  uint32_t nquad = M >> 2, tail = M & 3u;
  uint32_t gtid = (uint32_t)b * 1024u + (uint32_t)t;
  const uint32_t stride = (uint32_t)HWORK * 1024u;
  for (int mm = 0; mm < 3; ++mm) {
    uint32_t sk0 = ws->sub[1][2 - mm][0], sk1 = ws->sub[1][2 - mm][1];
    uint16_t* bid = ws->binid3[mm];
    for (int i = t; i < 4096; i += 1024) su.hist.lh32[i] = 0u;
    __syncthreads();
    for (uint32_t q = gtid; q < nquad; q += stride) {
      uint32_t j = q << 2;
      uint32_t k0 = tf_bits(sk0, sk1, j);
      uint32_t k1 = tf_bits(sk0, sk1, j + 1);
      uint32_t k2 = tf_bits(sk0, sk1, j + 2);
      uint32_t k3 = tf_bits(sk0, sk1, j + 3);
      uint32_t b0 = k0 >> BINSHIFT, b1 = k1 >> BINSHIFT;
      uint32_t b2 = k2 >> BINSHIFT, b3 = k3 >> BINSHIFT;
      *(ull*)(bid + j) = (ull)b0 | ((ull)b1 << 16) | ((ull)b2 << 32) | ((ull)b3 << 48);
      atomicAdd(&su.hist.lh32[b0 >> 1], (b0 & 1) ? 0x10000u : 1u);
      atomicAdd(&su.hist.lh32[b1 >> 1], (b1 & 1) ? 0x10000u : 1u);
      atomicAdd(&su.hist.lh32[b2 >> 1], (b2 & 1) ? 0x10000u : 1u);
      atomicAdd(&su.hist.lh32[b3 >> 1], (b3 & 1) ? 0x10000u : 1u);
    }
    if (gtid < tail) {
      uint32_t j = (nquad << 2) + gtid;
      uint32_t k0 = tf_bits(sk0, sk1, j);
      uint32_t b0 = k0 >> BINSHIFT;
      bid[j] = (uint16_t)b0;
      atomicAdd(&su.hist.lh32[b0 >> 1], (b0 & 1) ? 0x10000u : 1u);
    }
    __syncthreads();
    for (int i = t; i < 4096; i += 1024) ws->hist3Blk[mm][b][i] = su.hist.lh32[i];
    __syncthreads();
  }
  __threadfence();
  if (t == 0) atomicAdd(&ws->histDone, 1u);
  if (b >= HRED) return;

  // ---------------- reducers (blocks 0..47) ----------------
  if (t == 0) {
    while (atomicAdd(&ws->histDone, 0u) < (uint32_t)HWORK)
      __builtin_amdgcn_s_sleep(2);
  }
  __syncthreads();
  __threadfence();
  {
    uint32_t c = (uint32_t)b * 256u + ((uint32_t)t >> 2);   // 12288 columns
    uint32_t m_ = c >> 12, i_ = c & 4095u;
    uint32_t part = (uint32_t)t & 3u, lo = 0u, hi = 0u;
    for (uint32_t blk = part; blk < (uint32_t)HWORK; blk += 4u) {
      uint32_t v = ws->hist3Blk[m_][blk][i_];
      lo += v & 0xFFFFu; hi += v >> 16;
    }
    lo += __shfl_xor(lo, 1, 64); lo += __shfl_xor(lo, 2, 64);
    hi += __shfl_xor(hi, 1, 64); hi += __shfl_xor(hi, 2, 64);
    if (part == 0u) {
      ws->hist3[m_][2 * i_]     = lo;
      ws->hist3[m_][2 * i_ + 1] = hi;
    }
  }
  __threadfence();
  if (t == 0) atomicAdd(&ws->redDone, 1u);
  if (b != 0) return;

  // ---------------- scanloc round 0 (block 0) ----------------
  if (t == 0) {
    while (atomicAdd(&ws->redDone, 0u) < (uint32_t)HRED)
      __builtin_amdgcn_s_sleep(2);
  }
  __syncthreads();
  __threadfence();
  scanloc_body(ws, 0, su.scan.cumS, su.scan.part, su.scan.bsl, &su.scan.nsl);
}

// binid scan -> LDS compaction -> threefry for hits only -> range-reserved
// slotBuf writes.
__global__ __launch_bounds__(1024) void k_gather(WS* ws, int m) {
  __shared__ int bs[NBINS];
  __shared__ uint32_t hk[HCAP];
  __shared__ uint32_t hj[HCAP];
  __shared__ uint32_t scnt[MAXSLOT];
  __shared__ uint32_t sbase_[MAXSLOT];
  __shared__ uint32_t scur[MAXSLOT];
  __shared__ uint32_t hcnt;
  int t = threadIdx.x;
  for (int i = t; i < NBINS; i += blockDim.x) bs[i] = ws->binslot[i];
  if (t < MAXSLOT) scnt[t] = 0u;
  if (t == 0) hcnt = 0u;
  __syncthreads();
  uint32_t S = ws->M;
  uint32_t sk0 = ws->sub[1][2 - m][0], sk1 = ws->sub[1][2 - m][1];
  const uint16_t* bid = ws->binid3[m];
  uint32_t stride = gridDim.x * blockDim.x;
  for (uint32_t j = blockIdx.x * blockDim.x + t; j < S; j += stride) {
    int sl = bs[bid[j]];
    if (sl >= 0) {
      uint32_t h = atomicAdd(&hcnt, 1u);
      if (h < HCAP) {
        hj[h] = j;
      } else {
        uint32_t kk = tf_bits(sk0, sk1, j);
        uint32_t idx = atomicAdd(&ws->slotCnt[sl], 1u);
        if (idx < SLOTCAP) ws->slotBuf[sl][idx] = ((ull)kk << 24) | (ull)j;
      }
    }
  }
  __syncthreads();
  uint32_t n = hcnt < (uint32_t)HCAP ? hcnt : (uint32_t)HCAP;
  for (uint32_t h = t; h < n; h += blockDim.x) {
    uint32_t kk = tf_bits(sk0, sk1, hj[h]);
    hk[h] = kk;
    atomicAdd(&scnt[bs[kk >> BINSHIFT]], 1u);
  }
  __syncthreads();
  if (t < MAXSLOT) {
    scur[t] = 0u;
    if (scnt[t]) sbase_[t] = atomicAdd(&ws->slotCnt[t], scnt[t]);
  }
  __syncthreads();
  for (uint32_t h = t; h < n; h += blockDim.x) {
    uint32_t kk = hk[h], j = hj[h];
    int sl = bs[kk >> BINSHIFT];
    uint32_t idx = sbase_[sl] + atomicAdd(&scur[sl], 1u);
    if (idx < SLOTCAP) ws->slotBuf[sl][idx] = ((ull)kk << 24) | (ull)j;
  }
}

// Counting-sort select for slot=blockIdx.x; if doNext, last-finishing block
// runs scanloc for round m+1.
__global__ __launch_bounds__(1024) void k_selscan(WS* ws, int m, int doNext) {
  __shared__ ull      srt[SLOTCAP];
  __shared__ uint32_t hh[256];
  __shared__ uint32_t cum[257];
  __shared__ uint32_t cur[256];
  __shared__ uint32_t sb[256];
  __shared__ uint32_t cumS[NBINS + 1];
  __shared__ uint32_t part[1024];
  __shared__ int32_t  bslL[NBINS];
  __shared__ uint32_t nslL;
  __shared__ uint32_t lastF;
  int t = threadIdx.x;
  int slot = blockIdx.x;
  uint32_t nslots = ws->nslots;
  if ((uint32_t)slot < nslots) {
    uint32_t cnt = ws->slotCnt[slot];
    if (cnt > SLOTCAP) cnt = SLOTCAP;
    if (t < 256) hh[t] = 0u;
    __syncthreads();
    for (uint32_t i = t; i < cnt; i += 1024) {
      ull v = ws->slotBuf[slot][i];
      atomicAdd(&hh[(uint32_t)(v >> 35) & 255u], 1u);
    }
    __syncthreads();
    if (t < 256) sb[t] = hh[t];
    __syncthreads();
    for (int off = 1; off < 256; off <<= 1) {
      uint32_t add = (t >= off && t < 256) ? sb[t - off] : 0u;
      __syncthreads();
      if (t < 256) sb[t] += add;
      __syncthreads();
    }
    if (t == 0) cum[0] = 0u;
    if (t < 256) { cum[t + 1] = sb[t]; cur[t] = 0u; }
    __syncthreads();
    for (uint32_t i = t; i < cnt; i += 1024) {
      ull v = ws->slotBuf[slot][i];
      uint32_t bb = (uint32_t)(v >> 35) & 255u;
      uint32_t idx = cum[bb] + atomicAdd(&cur[bb], 1u);
      srt[idx] = v;
    }
    __syncthreads();
    uint32_t k = ws->kcnt[1];
    if (t < (int)k && ws->tslot[t] == (uint32_t)slot) {
      uint32_t tr = ws->tlocal[t];
      uint32_t lo = 0, hi = 256;
      while (hi - lo > 1u) {
        uint32_t mid = (lo + hi) >> 1;
        if (cum[mid] <= tr) lo = mid; else hi = mid;
      }
      uint32_t r2 = tr - cum[lo];
      uint32_t b0 = cum[lo], b1 = cum[lo + 1];
      for (uint32_t x = b0; x < b1; ++x) {
        ull vx = srt[x];
        uint32_t rank = 0;
        for (uint32_t y = b0; y < b1; ++y) rank += (srt[y] < vx) ? 1u : 0u;
        if (rank == r2) { ws->tgt[1][t] = (uint32_t)(vx & 0xFFFFFFull); break; }
      }
    }
  }
  if (doNext) {
    __threadfence();
    if (t == 0)
      lastF = (atomicAdd(&ws->selDone[m], 1u) == (uint32_t)(gridDim.x - 1)) ? 1u : 0u;
    __syncthreads();
    if (lastF) {
      __threadfence();
      scanloc_body(ws, m + 1, cumS, part, bslL, &nslL);
    }
  }
}

__device__ __forceinline__ float sl1(float dd) {
  float ad = fabsf(dd);
  return (ad < 1.0f) ? 0.5f * dd * dd : ad - 0.5f;
}

__global__ __launch_bounds__(256) void k_loss(WS* ws,
                                              const float* __restrict__ reg,
                                              const float* __restrict__ obj,
                                              const float4* __restrict__ tgtb,
                                              const float4* __restrict__ anch,
                                              float* out) {
  int s = threadIdx.x;
  uint32_t npos = ws->n_pos;
  double lr = 0.0, bc = 0.0;
  if (s < (int)npos) {
    uint32_t v = ws->tgt[0][s];
    uint32_t pa = ws->T[v];
    uint32_t i = pa >> 6, j = pa & 63u;
    float4 t = tgtb[j];
    float tcx = (t.x + t.z) * 0.5f, tcy = (t.y + t.w) * 0.5f;
    float tw = t.z - t.x, th = t.w - t.y;
    float4 a = anch[i];
    float r0 = (tcx - a.x) / a.z;
    float r1 = (tcy - a.y) / a.w;
    float r2 = logf(tw / a.z);
    float r3 = logf(th / a.w);
    lr = (double)sl1(reg[i * 4 + 0] - r0) + (double)sl1(reg[i * 4 + 1] - r1) +
         (double)sl1(reg[i * 4 + 2] - r2) + (double)sl1(reg[i * 4 + 3] - r3);
    float x = obj[i];
    bc = (double)(fmaxf(x, 0.0f) - x + log1pf(expf(-fabsf(x))));
  } else {
    uint32_t e = ws->tgt[1][s - (int)npos];
    uint32_t P = ws->P;
    uint32_t lo = 0, hi = P;
    while (lo < hi) {
      uint32_t mid = (lo + hi) >> 1;
      if (ws->T[mid] - mid > e) hi = mid; else lo = mid + 1;
    }
    uint32_t f = e + lo;
    uint32_t i = f >> 6;
    float x = obj[i];
    bc = (double)(fmaxf(x, 0.0f) + log1pf(expf(-fabsf(x))));
  }
  __shared__ double sA[256], sB[256];
  sA[s] = lr; sB[s] = bc;
  __syncthreads();
  for (int off = 128; off > 0; off >>= 1) {
    if (s < off) { sA[s] += sA[s + off]; sB[s] += sB[s + off]; }
    __syncthreads();
  }
  if (s == 0)
    out[0] = (float)(sA[0] * (10.0 / 2500.0) + sB[0] * (1.0 / 256.0));
}

extern "C" void kernel_launch(void* const* d_in, const int* in_sizes, int n_in,
                              void* d_out, int out_size, void* d_ws,
                              size_t ws_size, hipStream_t stream) {
  const float*  reg  = (const float*)d_in[0];
  const float*  obj  = (const float*)d_in[1];
  const float4* pred = (const float4*)d_in[2];
  const float4* tgtb = (const float4*)d_in[3];
  const float4* anch = (const float4*)d_in[4];
  float* out = (float*)d_out;
  WS* ws = (WS*)d_ws;
  (void)in_sizes; (void)n_in; (void)out_size; (void)ws_size;

  hipMemsetAsync(d_ws, 0, ZBYTES, stream);   // ctrl counters + lookback
  k_iou<<<CBLK, 256, 0, stream>>>(pred, tgtb, ws);
  k_scan_emit<<<CBLK, 256, 0, stream>>>(ws);
  k_big<<<256, 1024, 0, stream>>>(ws);       // hist x3 + reduce + scanloc0 + pos
  for (int m = 0; m < 3; ++m) {
    k_gather<<<CBLK, 1024, 0, stream>>>(ws, m);
    k_selscan<<<MAXSLOT, 1024, 0, stream>>>(ws, m, (m < 2) ? 1 : 0);
  }
  k_loss<<<1, 256, 0, stream>>>(ws, reg, obj, tgtb, anch, out);
}

// Round 12
// 371.429 us; speedup vs baseline: 1.2418x; 1.2418x over previous
//
#include <hip/hip_runtime.h>
#include <stdint.h>

// ---------------------------------------------------------------------------
// RPN loss: IoU>0.7 matching + argmax fix + exact JAX threefry sampling
// (partitionable PRNG path) + smooth-L1 + BCE, all on device.
// R1-R7: algorithmic fixes (2785 -> 314us). R8-R11: launch collapse.
// R11 post-mortem: k_big's 104KB LDS union halved occupancy (1 blk/CU,
// VALUBusy 62->33%) -> hist 2x slower. R12:
//  - k_histA: 16KB LDS packed-u16 hist, plain slice stores (hist3Blk),
//    u64 binid stores, 512 blocks = 2 blk/CU.
//  - k_redscan (49 blocks): 0..47 coalesced-reduce hist3Blk -> hist3,
//    last-done block runs scanloc0; block 48 runs the pos chain.
//  - k_gather: binid scanned as u64 quads (was scalar u16).
// ---------------------------------------------------------------------------

#define N_PRED   131072
#define NBOXK    64
#define NM_TOT   8388608u          // N_PRED * NBOXK
#define TCAP     65536
#define NBINS    8192
#define BINSHIFT 19                // key >> 19 -> 13-bit bin
#define SLOTCAP  3072
#define MAXSLOT  192
#define HCAP     2048              // per-block LDS hit buffer (gather)
#define CBLK     512               // iou/scan blocks
#define POSCAP   32                // per-bin candidate cap in pos chain
#define HBLK     512               // hist worker blocks
#define HRED     48                // reducer blocks in k_redscan

typedef unsigned long long ull;

struct WS {
  // ---- zeroed by hipMemsetAsync at the head of every launch ----
  uint32_t iouDone, redDone, selDone[2], zpad[4];             // 32B
  ull      lookback[CBLK];                                    // 4KB
  // ---- end zero region (ZBYTES) ----
  uint32_t P, M, n_pos, n_neg;
  uint32_t R[2], S[2], kcnt[2];
  uint32_t sub[2][3][2];            // per-round subkeys
  uint32_t nslots;
  uint32_t hist3[3][NBINS];         // reduced hists (plain-written)
  ull      colBestBlk[CBLK][NBOXK]; // per-block iou argmax partials
  ull      maskWords[N_PRED];
  uint32_t T[TCAP];
  uint32_t tgt[2][256];
  int32_t  binslot[NBINS];
  int32_t  tslot[256];
  uint32_t tlocal[256];
  uint32_t slotCnt[MAXSLOT];
  ull      slotBuf[MAXSLOT][SLOTCAP];
  uint32_t hist3Blk[3][HBLK][4096]; // per-block u16-pair hist slices, 25MB
  uint16_t binid3[3][NM_TOT];       // 50MB bin-id cache (ws is 256MB)
};
#define ZBYTES (32 + CBLK*8)

// rotate-left via v_alignbit_b32 (single VALU op)
__device__ __forceinline__ uint32_t rotl(uint32_t x, uint32_t r) {
  return __builtin_amdgcn_alignbit(x, x, 32u - r);
}

// Threefry-2x32-20, matches JAX reference implementation exactly.
__device__ __forceinline__ void tf2(uint32_t k0, uint32_t k1,
                                    uint32_t& x0, uint32_t& x1) {
  uint32_t k2 = k0 ^ k1 ^ 0x1BD11BDAu;
  x0 += k0; x1 += k1;
#define QR(r) { x0 += x1; x1 = rotl(x1, r); x1 ^= x0; }
  QR(13) QR(15) QR(26) QR(6)  x0 += k1; x1 += k2 + 1u;
  QR(17) QR(29) QR(16) QR(24) x0 += k2; x1 += k0 + 2u;
  QR(13) QR(15) QR(26) QR(6)  x0 += k0; x1 += k1 + 3u;
  QR(17) QR(29) QR(16) QR(24) x0 += k1; x1 += k2 + 4u;
  QR(13) QR(15) QR(26) QR(6)  x0 += k2; x1 += k0 + 5u;
#undef QR
}

__device__ __forceinline__ uint32_t tf_bits(uint32_t k0, uint32_t k1, uint32_t p) {
  uint32_t a = 0u, b = p;
  tf2(k0, k1, a, b);
  return a ^ b;
}

__device__ __forceinline__ ull umax64(ull a, ull b) { return a > b ? a : b; }

// IoU mask + per-column argmax; per-block partials; last block reduces and
// applies the "need" fixup. Lane l owns column l (zero shuffles).
__global__ __launch_bounds__(256) void k_iou(const float4* __restrict__ pred,
                                             const float4* __restrict__ tgtb,
                                             WS* ws) {
  __shared__ float4 sp[256];
  __shared__ ull cb[NBOXK];
  __shared__ ull red[4][NBOXK];
  __shared__ uint32_t lastF;
  int t = threadIdx.x;
  int lane = t & 63;
  int w = t >> 6;
  int rowBase = blockIdx.x * 256;
  sp[t] = pred[rowBase + t];
  if (t < NBOXK) cb[t] = 0ull;
  float4 tb = tgtb[lane];
  float ta = __fmul_rn(__fsub_rn(tb.z, tb.x), __fsub_rn(tb.w, tb.y));
  __syncthreads();
  ull myWord = 0ull;
  float bestI = -1.0f;
  uint32_t bestRow = 0u;
  int wbase = w * 64;
  for (int r = 0; r < 64; ++r) {
    float4 p = sp[wbase + r];
    float pa = __fmul_rn(__fsub_rn(p.z, p.x), __fsub_rn(p.w, p.y));
    float ltx = fmaxf(p.x, tb.x), lty = fmaxf(p.y, tb.y);
    float rbx = fminf(p.z, tb.z), rby = fminf(p.w, tb.w);
    float wx = fmaxf(__fsub_rn(rbx, ltx), 0.0f);
    float wy = fmaxf(__fsub_rn(rby, lty), 0.0f);
    float inter = __fmul_rn(wx, wy);
    float uni = __fsub_rn(__fadd_rn(pa, ta), inter);
    float iou = __fdiv_rn(inter, uni);
    ull bal = __ballot(iou > 0.7f);
    if (lane == r) myWord = bal;
    if (iou > bestI) { bestI = iou; bestRow = (uint32_t)(rowBase + wbase + r); }
  }
  ws->maskWords[rowBase + wbase + lane] = myWord;
  ull pk = ((ull)__float_as_uint(bestI) << 32) | (ull)(~bestRow);
  atomicMax(&cb[lane], pk);
  __syncthreads();
  if (t < NBOXK) ws->colBestBlk[blockIdx.x][t] = cb[t];
  __threadfence();
  if (t == 0)
    lastF = (atomicAdd(&ws->iouDone, 1u) == (uint32_t)(gridDim.x - 1)) ? 1u : 0u;
  __syncthreads();
  if (lastF) {
    __threadfence();
    int c = t & 63, q = t >> 6;
    ull best = 0ull;
    for (int b = q; b < CBLK; b += 4) best = umax64(best, ws->colBestBlk[b][c]);
    red[q][c] = best;
    __syncthreads();
    if (t < NBOXK) {
      ull m_ = umax64(umax64(red[0][t], red[1][t]), umax64(red[2][t], red[3][t]));
      float bi = __uint_as_float((uint32_t)(m_ >> 32));
      if (!(bi > 0.7f)) {
        uint32_t row = ~(uint32_t)(m_ & 0xFFFFFFFFu);
        atomicOr(&ws->maskWords[row], 1ull << t);
      }
    }
  }
}

// Fused count + global scan (windowed wave-parallel lookback) + ordered emit;
// block 511 does the scalar/PRNG setup.
__global__ __launch_bounds__(256) void k_scan_emit(WS* ws) {
  __shared__ uint32_t sm[256];
  __shared__ uint32_t exclS;
  int t = threadIdx.x, b = blockIdx.x;
  int row = b * 256 + t;
  ull w = ws->maskWords[row];
  uint32_t c = (uint32_t)__popcll(w);
  sm[t] = c;
  __syncthreads();
  for (int off = 1; off < 256; off <<= 1) {
    uint32_t add = (t >= off) ? sm[t - off] : 0u;
    __syncthreads();
    sm[t] += add;
    __syncthreads();
  }
  uint32_t mySum = sm[255];
  if (t == 0) {
    if (b == 0) {
      atomicExch(&ws->lookback[0], (2ull << 32) | (ull)mySum);
      exclS = 0u;
    } else {
      atomicExch(&ws->lookback[b], (1ull << 32) | (ull)mySum);
    }
    __threadfence();
  }
  if (b > 0 && t < 64) {
    int i = b - 1;
    uint32_t run = 0u;
    while (true) {
      int idx = i - t;
      ull x = (idx >= 0) ? atomicAdd(&ws->lookback[idx], 0ull) : (2ull << 32);
      uint32_t st = (uint32_t)(x >> 32);
      ull b2 = __ballot(st == 2u);
      ull b0 = __ballot(st == 0u);
      int f2 = (b2 == 0ull) ? 64 : (__ffsll((long long)b2) - 1);
      int f0 = (b0 == 0ull) ? 64 : (__ffsll((long long)b0) - 1);
      if (f0 < f2) continue;
      uint32_t v = (t <= f2) ? (uint32_t)x : 0u;
#pragma unroll
      for (int o = 32; o > 0; o >>= 1) v += __shfl_xor(v, o, 64);
      run += v;
      if (f2 < 64) break;
      i -= 64;
    }
    if (t == 0) {
      atomicExch(&ws->lookback[b], (2ull << 32) | (ull)(run + mySum));
      exclS = run;
    }
  }
  __syncthreads();
  uint32_t off0 = exclS + sm[t] - c;
  while (w) {
    int bit = __ffsll((long long)w) - 1;
    w &= (w - 1);
    if (off0 < TCAP) ws->T[off0] = ((uint32_t)row << 6) | (uint32_t)bit;
    off0++;
  }
  if (b == CBLK - 1) {
    ws->tgt[0][t] = (uint32_t)t;
    ws->tgt[1][t] = (uint32_t)t;
    if (t == 0) {
      uint32_t total = exclS + mySum;
      uint32_t P = total < (uint32_t)TCAP ? total : (uint32_t)TCAP;
      uint32_t M = NM_TOT - P;
      uint32_t npos = P < 128u ? P : 128u;
      ws->P = P; ws->M = M;
      ws->n_pos = npos; ws->n_neg = 256u - npos;
      ws->S[0] = P; ws->S[1] = M;
      ws->kcnt[0] = npos; ws->kcnt[1] = 256u - npos;
      const double LOGU = 22.18070977791825;  // log(2^32 - 1)
      for (int d = 0; d < 2; ++d) {
        uint32_t Sd = ws->S[d];
        int R = 0;
        if (Sd > 1u) {
          R = (int)ceil(3.0 * log((double)Sd) / LOGU);
          if (R < 1) R = 1;
          if (R > 3) R = 3;
        }
        ws->R[d] = (uint32_t)R;
        uint32_t ck0, ck1;
        { uint32_t a = 0u, bb = (uint32_t)d; tf2(0u, 42u, a, bb); ck0 = a; ck1 = bb; }
        for (int rr = 0; rr < 3; ++rr) {
          uint32_t s0 = 0u, s1 = 1u; tf2(ck0, ck1, s0, s1);
          ws->sub[d][rr][0] = s0; ws->sub[d][rr][1] = s1;
          uint32_t n0 = 0u, n1 = 0u; tf2(ck0, ck1, n0, n1);
          ck0 = n0; ck1 = n1;
        }
      }
    }
  }
}

// All 3 neg-round hists + bin-id caches. 16KB LDS (packed u16-pair), plain
// slice flush to hist3Blk (no global atomics). 512 blocks = 2 blk/CU.
__global__ __launch_bounds__(1024) void k_histA(WS* ws) {
  __shared__ uint32_t lh[4096];
  const uint32_t M = ws->M;
  uint32_t nquad = M >> 2, tail = M & 3u;
  uint32_t gtid = blockIdx.x * 1024u + threadIdx.x;
  const uint32_t stride = (uint32_t)HBLK * 1024u;
  for (int mm = 0; mm < 3; ++mm) {
    uint32_t sk0 = ws->sub[1][2 - mm][0], sk1 = ws->sub[1][2 - mm][1];
    uint16_t* bid = ws->binid3[mm];
    for (int i = threadIdx.x; i < 4096; i += 1024) lh[i] = 0u;
    __syncthreads();
    for (uint32_t q = gtid; q < nquad; q += stride) {
      uint32_t j = q << 2;
      uint32_t k0 = tf_bits(sk0, sk1, j);
      uint32_t k1 = tf_bits(sk0, sk1, j + 1);
      uint32_t k2 = tf_bits(sk0, sk1, j + 2);
      uint32_t k3 = tf_bits(sk0, sk1, j + 3);
      uint32_t b0 = k0 >> BINSHIFT, b1 = k1 >> BINSHIFT;
      uint32_t b2 = k2 >> BINSHIFT, b3 = k3 >> BINSHIFT;
      *(ull*)(bid + j) = (ull)b0 | ((ull)b1 << 16) | ((ull)b2 << 32) | ((ull)b3 << 48);
      atomicAdd(&lh[b0 >> 1], (b0 & 1) ? 0x10000u : 1u);
      atomicAdd(&lh[b1 >> 1], (b1 & 1) ? 0x10000u : 1u);
      atomicAdd(&lh[b2 >> 1], (b2 & 1) ? 0x10000u : 1u);
      atomicAdd(&lh[b3 >> 1], (b3 & 1) ? 0x10000u : 1u);
    }
    if (gtid < tail) {
      uint32_t j = (nquad << 2) + gtid;
      uint32_t k0 = tf_bits(sk0, sk1, j);
      uint32_t b0 = k0 >> BINSHIFT;
      bid[j] = (uint16_t)b0;
      atomicAdd(&lh[b0 >> 1], (b0 & 1) ? 0x10000u : 1u);
    }
    __syncthreads();
    for (int i = threadIdx.x; i < 4096; i += 1024)
      ws->hist3Blk[mm][blockIdx.x][i] = lh[i];
    __syncthreads();
  }
}

// scanloc body (1024 threads): LDS scan of hist3[m], per-target binary
// search, LDS bin dedup; writes binslot map + zeroes slotCnt/nslots.
__device__ void scanloc_body(WS* ws, int m, uint32_t* cumS, uint32_t* part,
                             int32_t* bslL, uint32_t* nslL) {
  int t = threadIdx.x;
  const int E = NBINS / 1024;
  uint32_t lv[E];
  uint32_t s = 0;
  uint32_t base = (uint32_t)t * E;
#pragma unroll
  for (int e = 0; e < E; ++e) { lv[e] = ws->hist3[m][base + e]; s += lv[e]; }
  part[t] = s;
  for (int i = t; i < NBINS; i += 1024) bslL[i] = -1;
  if (t == 0) *nslL = 0u;
  __syncthreads();
  for (int off = 1; off < 1024; off <<= 1) {
    uint32_t add = (t >= off) ? part[t - off] : 0u;
    __syncthreads();
    part[t] += add;
    __syncthreads();
  }
  uint32_t run = part[t] - s;
#pragma unroll
  for (int e = 0; e < E; ++e) { cumS[base + e] = run; run += lv[e]; }
  if (t == 1023) cumS[NBINS] = run;
  __syncthreads();
  uint32_t k = ws->kcnt[1];
  uint32_t lo = 0; int old = 0;
  if (t < (int)k) {
    uint32_t tr = ws->tgt[1][t];
    uint32_t hi = NBINS;
    while (hi - lo > 1u) {
      uint32_t mid = (lo + hi) >> 1;
      if (cumS[mid] <= tr) lo = mid; else hi = mid;
    }
    ws->tlocal[t] = tr - cumS[lo];
    old = atomicCAS(&bslL[lo], -1, (int)(0x10000u + (uint32_t)t));
  }
  __syncthreads();
  if (t < (int)k && old == -1) {
    uint32_t sl = atomicAdd(nslL, 1u);
    bslL[lo] = (int)sl;
  }
  __syncthreads();
  if (t < (int)k) ws->tslot[t] = (uint32_t)bslL[lo];
  for (int i = t; i < NBINS; i += 1024) ws->binslot[i] = bslL[i];
  if (t < MAXSLOT) ws->slotCnt[t] = 0u;
  if (t == 0) ws->nslots = *nslL;
}

union RedU {
  struct { uint32_t plo[4][256], phi[4][256]; } red;                  // 8KB
  struct { uint32_t cumS[NBINS + 1]; uint32_t part[1024];
           int32_t bsl[NBINS]; uint32_t nsl; } scan;                  // 68KB
  struct { uint32_t h8[NBINS]; uint32_t part[1024]; int32_t bsl[NBINS];
           ull sbuf[128][POSCAP]; uint32_t scntL[128];
           uint32_t tg[256], tlo[256], tsl[256]; uint32_t nsl; } pos; // 104KB
};

// blocks 0..47: coalesced reduce hist3Blk -> hist3; last-done block runs
// scanloc round 0. Block 48: whole pos chain. 49 blocks, co-resident.
__global__ __launch_bounds__(1024) void k_redscan(WS* ws) {
  __shared__ RedU su;
  __shared__ uint32_t lastF;
  int b = blockIdx.x, t = threadIdx.x;

  if (b == HRED) {
    // ---------------- pos chain ----------------
    int R = (int)ws->R[0];
    uint32_t P = ws->P;
    uint32_t k = ws->kcnt[0];
    if (R < 1) return;
    if (t < 256) su.pos.tg[t] = (uint32_t)t;
    __syncthreads();
    for (int r = R; r >= 1; --r) {
      uint32_t sk0 = ws->sub[0][r - 1][0], sk1 = ws->sub[0][r - 1][1];
      for (int i = t; i < NBINS; i += 1024) su.pos.h8[i] = 0u;
      __syncthreads();
      for (uint32_t j = t; j < P; j += 1024)
        atomicAdd(&su.pos.h8[tf_bits(sk0, sk1, j) >> BINSHIFT], 1u);
      __syncthreads();
      uint32_t lv[NBINS / 1024];
      uint32_t s = 0;
      uint32_t base = (uint32_t)t * (NBINS / 1024);
#pragma unroll
      for (int e = 0; e < NBINS / 1024; ++e) { lv[e] = su.pos.h8[base + e]; s += lv[e]; }
      su.pos.part[t] = s;
      __syncthreads();
      for (int off = 1; off < 1024; off <<= 1) {
        uint32_t add = (t >= off) ? su.pos.part[t - off] : 0u;
        __syncthreads();
        su.pos.part[t] += add;
        __syncthreads();
      }
      uint32_t run = su.pos.part[t] - s;
#pragma unroll
      for (int e = 0; e < NBINS / 1024; ++e) { su.pos.h8[base + e] = run; run += lv[e]; }
      for (int i = t; i < NBINS; i += 1024) su.pos.bsl[i] = -1;
      if (t == 0) su.pos.nsl = 0u;
      if (t < 128) su.pos.scntL[t] = 0u;
      __syncthreads();
      uint32_t lo = 0; int old = 0;
      if (t < (int)k) {
        uint32_t tr = su.pos.tg[t];
        uint32_t hi = NBINS;
        while (hi - lo > 1u) {
          uint32_t mid = (lo + hi) >> 1;
          if (su.pos.h8[mid] <= tr) lo = mid; else hi = mid;
        }
        su.pos.tlo[t] = tr - su.pos.h8[lo];
        old = atomicCAS(&su.pos.bsl[lo], -1, (int)(0x10000u + (uint32_t)t));
      }
      __syncthreads();
      if (t < (int)k && old == -1) {
        uint32_t sl = atomicAdd(&su.pos.nsl, 1u);
        su.pos.bsl[lo] = (int)sl;
      }
      __syncthreads();
      if (t < (int)k) su.pos.tsl[t] = (uint32_t)su.pos.bsl[lo];
      __syncthreads();
      for (uint32_t j = t; j < P; j += 1024) {
        uint32_t kk = tf_bits(sk0, sk1, j);
        int sl = su.pos.bsl[kk >> BINSHIFT];
        if (sl >= 0) {
          uint32_t idx = atomicAdd(&su.pos.scntL[sl], 1u);
          if (idx < POSCAP) su.pos.sbuf[sl][idx] = ((ull)kk << 24) | (ull)j;
        }
      }
      __syncthreads();
      if (t < (int)k) {
        uint32_t sl = su.pos.tsl[t], r2 = su.pos.tlo[t];
        uint32_t cn = su.pos.scntL[sl] < POSCAP ? su.pos.scntL[sl] : POSCAP;
        for (uint32_t x = 0; x < cn; ++x) {
          ull vx = su.pos.sbuf[sl][x];
          uint32_t rank = 0;
          for (uint32_t y = 0; y < cn; ++y) rank += (su.pos.sbuf[sl][y] < vx) ? 1u : 0u;
          if (rank == r2) { su.pos.tg[t] = (uint32_t)(vx & 0xFFFFFFull); break; }
        }
      }
      __syncthreads();
    }
    if (t < (int)k) ws->tgt[0][t] = su.pos.tg[t];
    return;
  }

  // ---------------- reducers (blocks 0..47) ----------------
  {
    uint32_t c = (uint32_t)b * 256u + ((uint32_t)t & 255u);
    uint32_t m_ = c >> 12, i_ = c & 4095u;
    uint32_t p = (uint32_t)t >> 8;
    uint32_t lo = 0u, hi = 0u;
    for (uint32_t blk = p; blk < (uint32_t)HBLK; blk += 4u) {
      uint32_t v = ws->hist3Blk[m_][blk][i_];
      lo += v & 0xFFFFu; hi += v >> 16;
    }
    su.red.plo[p][t & 255] = lo;
    su.red.phi[p][t & 255] = hi;
  }
  __syncthreads();
  if (t < 256) {
    uint32_t l2 = su.red.plo[0][t] + su.red.plo[1][t] + su.red.plo[2][t] + su.red.plo[3][t];
    uint32_t h2 = su.red.phi[0][t] + su.red.phi[1][t] + su.red.phi[2][t] + su.red.phi[3][t];
    uint32_t cc = (uint32_t)b * 256u + (uint32_t)t;
    uint32_t mm = cc >> 12, ii = cc & 4095u;
    ws->hist3[mm][2 * ii]     = l2;
    ws->hist3[mm][2 * ii + 1] = h2;
  }
  __threadfence();
  __syncthreads();
  if (t == 0)
    lastF = (atomicAdd(&ws->redDone, 1u) == (uint32_t)(HRED - 1)) ? 1u : 0u;
  __syncthreads();
  if (lastF) {
    __threadfence();
    scanloc_body(ws, 0, su.scan.cumS, su.scan.part, su.scan.bsl, &su.scan.nsl);
  }
}

// binid scanned as u64 quads -> LDS compaction -> threefry for hits only ->
// range-reserved slotBuf writes.
__global__ __launch_bounds__(1024) void k_gather(WS* ws, int m) {
  __shared__ int bs[NBINS];
  __shared__ uint32_t hk[HCAP];
  __shared__ uint32_t hj[HCAP];
  __shared__ uint32_t scnt[MAXSLOT];
  __shared__ uint32_t sbase_[MAXSLOT];
  __shared__ uint32_t scur[MAXSLOT];
  __shared__ uint32_t hcnt;
  int t = threadIdx.x;
  for (int i = t; i < NBINS; i += blockDim.x) bs[i] = ws->binslot[i];
  if (t < MAXSLOT) scnt[t] = 0u;
  if (t == 0) hcnt = 0u;
  __syncthreads();
  uint32_t S = ws->M;
  uint32_t sk0 = ws->sub[1][2 - m][0], sk1 = ws->sub[1][2 - m][1];
  const uint16_t* bid = ws->binid3[m];
  const ull* bid4 = (const ull*)bid;
  uint32_t nquad = S >> 2, tail = S & 3u;
  uint32_t gtid = blockIdx.x * blockDim.x + t;
  uint32_t stride = gridDim.x * blockDim.x;
  for (uint32_t q = gtid; q < nquad; q += stride) {
    ull v4 = bid4[q];
    uint32_t j0 = q << 2;
#pragma unroll
    for (int e = 0; e < 4; ++e) {
      uint32_t bb = (uint32_t)(v4 >> (16 * e)) & 0xFFFFu;
      int sl = bs[bb];
      if (sl >= 0) {
        uint32_t h = atomicAdd(&hcnt, 1u);
        if (h < HCAP) {
          hj[h] = j0 + (uint32_t)e;
        } else {
          uint32_t kk = tf_bits(sk0, sk1, j0 + (uint32_t)e);
          uint32_t idx = atomicAdd(&ws->slotCnt[sl], 1u);
          if (idx < SLOTCAP) ws->slotBuf[sl][idx] = ((ull)kk << 24) | (ull)(j0 + e);
        }
      }
    }
  }
  if (gtid < tail) {
    uint32_t j = (nquad << 2) + gtid;
    int sl = bs[bid[j]];
    if (sl >= 0) {
      uint32_t h = atomicAdd(&hcnt, 1u);
      if (h < HCAP) {
        hj[h] = j;
      } else {
        uint32_t kk = tf_bits(sk0, sk1, j);
        uint32_t idx = atomicAdd(&ws->slotCnt[sl], 1u);
        if (idx < SLOTCAP) ws->slotBuf[sl][idx] = ((ull)kk << 24) | (ull)j;
      }
    }
  }
  __syncthreads();
  uint32_t n = hcnt < (uint32_t)HCAP ? hcnt : (uint32_t)HCAP;
  for (uint32_t h = t; h < n; h += blockDim.x) {
    uint32_t kk = tf_bits(sk0, sk1, hj[h]);
    hk[h] = kk;
    atomicAdd(&scnt[bs[kk >> BINSHIFT]], 1u);
  }
  __syncthreads();
  if (t < MAXSLOT) {
    scur[t] = 0u;
    if (scnt[t]) sbase_[t] = atomicAdd(&ws->slotCnt[t], scnt[t]);
  }
  __syncthreads();
  for (uint32_t h = t; h < n; h += blockDim.x) {
    uint32_t kk = hk[h], j = hj[h];
    int sl = bs[kk >> BINSHIFT];
    uint32_t idx = sbase_[sl] + atomicAdd(&scur[sl], 1u);
    if (idx < SLOTCAP) ws->slotBuf[sl][idx] = ((ull)kk << 24) | (ull)j;
  }
}

// Counting-sort select for slot=blockIdx.x; if doNext, last-finishing block
// runs scanloc for round m+1.
__global__ __launch_bounds__(1024) void k_selscan(WS* ws, int m, int doNext) {
  __shared__ ull      srt[SLOTCAP];
  __shared__ uint32_t hh[256];
  __shared__ uint32_t cum[257];
  __shared__ uint32_t cur[256];
  __shared__ uint32_t sb[256];
  __shared__ uint32_t cumS[NBINS + 1];
  __shared__ uint32_t part[1024];
  __shared__ int32_t  bslL[NBINS];
  __shared__ uint32_t nslL;
  __shared__ uint32_t lastF;
  int t = threadIdx.x;
  int slot = blockIdx.x;
  uint32_t nslots = ws->nslots;
  if ((uint32_t)slot < nslots) {
    uint32_t cnt = ws->slotCnt[slot];
    if (cnt > SLOTCAP) cnt = SLOTCAP;
    if (t < 256) hh[t] = 0u;
    __syncthreads();
    for (uint32_t i = t; i < cnt; i += 1024) {
      ull v = ws->slotBuf[slot][i];
      atomicAdd(&hh[(uint32_t)(v >> 35) & 255u], 1u);
    }
    __syncthreads();
    if (t < 256) sb[t] = hh[t];
    __syncthreads();
    for (int off = 1; off < 256; off <<= 1) {
      uint32_t add = (t >= off && t < 256) ? sb[t - off] : 0u;
      __syncthreads();
      if (t < 256) sb[t] += add;
      __syncthreads();
    }
    if (t == 0) cum[0] = 0u;
    if (t < 256) { cum[t + 1] = sb[t]; cur[t] = 0u; }
    __syncthreads();
    for (uint32_t i = t; i < cnt; i += 1024) {
      ull v = ws->slotBuf[slot][i];
      uint32_t bb = (uint32_t)(v >> 35) & 255u;
      uint32_t idx = cum[bb] + atomicAdd(&cur[bb], 1u);
      srt[idx] = v;
    }
    __syncthreads();
    uint32_t k = ws->kcnt[1];
    if (t < (int)k && ws->tslot[t] == (uint32_t)slot) {
      uint32_t tr = ws->tlocal[t];
      uint32_t lo = 0, hi = 256;
      while (hi - lo > 1u) {
        uint32_t mid = (lo + hi) >> 1;
        if (cum[mid] <= tr) lo = mid; else hi = mid;
      }
      uint32_t r2 = tr - cum[lo];
      uint32_t b0 = cum[lo], b1 = cum[lo + 1];
      for (uint32_t x = b0; x < b1; ++x) {
        ull vx = srt[x];
        uint32_t rank = 0;
        for (uint32_t y = b0; y < b1; ++y) rank += (srt[y] < vx) ? 1u : 0u;
        if (rank == r2) { ws->tgt[1][t] = (uint32_t)(vx & 0xFFFFFFull); break; }
      }
    }
  }
  if (doNext) {
    __threadfence();
    if (t == 0)
      lastF = (atomicAdd(&ws->selDone[m], 1u) == (uint32_t)(gridDim.x - 1)) ? 1u : 0u;
    __syncthreads();
    if (lastF) {
      __threadfence();
      scanloc_body(ws, m + 1, cumS, part, bslL, &nslL);
    }
  }
}

__device__ __forceinline__ float sl1(float dd) {
  float ad = fabsf(dd);
  return (ad < 1.0f) ? 0.5f * dd * dd : ad - 0.5f;
}

__global__ __launch_bounds__(256) void k_loss(WS* ws,
                                              const float* __restrict__ reg,
                                              const float* __restrict__ obj,
                                              const float4* __restrict__ tgtb,
                                              const float4* __restrict__ anch,
                                              float* out) {
  int s = threadIdx.x;
  uint32_t npos = ws->n_pos;
  double lr = 0.0, bc = 0.0;
  if (s < (int)npos) {
    uint32_t v = ws->tgt[0][s];
    uint32_t pa = ws->T[v];
    uint32_t i = pa >> 6, j = pa & 63u;
    float4 t = tgtb[j];
    float tcx = (t.x + t.z) * 0.5f, tcy = (t.y + t.w) * 0.5f;
    float tw = t.z - t.x, th = t.w - t.y;
    float4 a = anch[i];
    float r0 = (tcx - a.x) / a.z;
    float r1 = (tcy - a.y) / a.w;
    float r2 = logf(tw / a.z);
    float r3 = logf(th / a.w);
    lr = (double)sl1(reg[i * 4 + 0] - r0) + (double)sl1(reg[i * 4 + 1] - r1) +
         (double)sl1(reg[i * 4 + 2] - r2) + (double)sl1(reg[i * 4 + 3] - r3);
    float x = obj[i];
    bc = (double)(fmaxf(x, 0.0f) - x + log1pf(expf(-fabsf(x))));
  } else {
    uint32_t e = ws->tgt[1][s - (int)npos];
    uint32_t P = ws->P;
    uint32_t lo = 0, hi = P;
    while (lo < hi) {
      uint32_t mid = (lo + hi) >> 1;
      if (ws->T[mid] - mid > e) hi = mid; else lo = mid + 1;
    }
    uint32_t f = e + lo;
    uint32_t i = f >> 6;
    float x = obj[i];
    bc = (double)(fmaxf(x, 0.0f) + log1pf(expf(-fabsf(x))));
  }
  __shared__ double sA[256], sB[256];
  sA[s] = lr; sB[s] = bc;
  __syncthreads();
  for (int off = 128; off > 0; off >>= 1) {
    if (s < off) { sA[s] += sA[s + off]; sB[s] += sB[s + off]; }
    __syncthreads();
  }
  if (s == 0)
    out[0] = (float)(sA[0] * (10.0 / 2500.0) + sB[0] * (1.0 / 256.0));
}

extern "C" void kernel_launch(void* const* d_in, const int* in_sizes, int n_in,
                              void* d_out, int out_size, void* d_ws,
                              size_t ws_size, hipStream_t stream) {
  const float*  reg  = (const float*)d_in[0];
  const float*  obj  = (const float*)d_in[1];
  const float4* pred = (const float4*)d_in[2];
  const float4* tgtb = (const float4*)d_in[3];
  const float4* anch = (const float4*)d_in[4];
  float* out = (float*)d_out;
  WS* ws = (WS*)d_ws;
  (void)in_sizes; (void)n_in; (void)out_size; (void)ws_size;

  hipMemsetAsync(d_ws, 0, ZBYTES, stream);   // ctrl counters + lookback
  k_iou<<<CBLK, 256, 0, stream>>>(pred, tgtb, ws);
  k_scan_emit<<<CBLK, 256, 0, stream>>>(ws);
  k_histA<<<HBLK, 1024, 0, stream>>>(ws);
  k_redscan<<<HRED + 1, 1024, 0, stream>>>(ws);  // reduce + scanloc0 + pos
  for (int m = 0; m < 3; ++m) {
    k_gather<<<CBLK, 1024, 0, stream>>>(ws, m);
    k_selscan<<<MAXSLOT, 1024, 0, stream>>>(ws, m, (m < 2) ? 1 : 0);
  }
  k_loss<<<1, 256, 0, stream>>>(ws, reg, obj, tgtb, anch, out);
}

// Round 13
// 239.244 us; speedup vs baseline: 1.9279x; 1.5525x over previous
//
#include <hip/hip_runtime.h>
#include <stdint.h>

// ---------------------------------------------------------------------------
// RPN loss: IoU>0.7 matching + argmax fix + exact JAX threefry sampling
// (partitionable PRNG path) + smooth-L1 + BCE, all on device.
// R1-R7: algorithmic fixes (2785 -> 314us). R8-R12: launch collapse + hist
// occupancy repair (371us).
// R12 post-mortem: k_iou 79us = (a) __threadfence by ALL 2048 waves (per-wave
// L2 writeback storm, ~+39us since R8) + (b) 64 serial dependent ds_read_b128
// per wave with 2 waves/SIMD (~40us latency floor since R7).
// R13: k_iou 8-deep row prefetch + 1024-thr blocks (4 waves/SIMD) + t0-only
// release fence after syncthreads. Same fence repair in redscan/selscan.
// ---------------------------------------------------------------------------

#define N_PRED   131072
#define NBOXK    64
#define NM_TOT   8388608u          // N_PRED * NBOXK
#define TCAP     65536
#define NBINS    8192
#define BINSHIFT 19                // key >> 19 -> 13-bit bin
#define SLOTCAP  3072
#define MAXSLOT  192
#define HCAP     2048              // per-block LDS hit buffer (gather)
#define CBLK     512               // scan blocks
#define IBLK     128               // iou blocks (1024 thr each)
#define POSCAP   32                // per-bin candidate cap in pos chain
#define HBLK     512               // hist worker blocks
#define HRED     48                // reducer blocks in k_redscan

typedef unsigned long long ull;

struct WS {
  // ---- zeroed by hipMemsetAsync at the head of every launch ----
  uint32_t iouDone, redDone, selDone[2], zpad[4];             // 32B
  ull      lookback[CBLK];                                    // 4KB
  // ---- end zero region (ZBYTES) ----
  uint32_t P, M, n_pos, n_neg;
  uint32_t R[2], S[2], kcnt[2];
  uint32_t sub[2][3][2];            // per-round subkeys
  uint32_t nslots;
  uint32_t hist3[3][NBINS];         // reduced hists (plain-written)
  ull      colBestBlk[IBLK][NBOXK]; // per-block iou argmax partials
  ull      maskWords[N_PRED];
  uint32_t T[TCAP];
  uint32_t tgt[2][256];
  int32_t  binslot[NBINS];
  int32_t  tslot[256];
  uint32_t tlocal[256];
  uint32_t slotCnt[MAXSLOT];
  ull      slotBuf[MAXSLOT][SLOTCAP];
  uint32_t hist3Blk[3][HBLK][4096]; // per-block u16-pair hist slices, 25MB
  uint16_t binid3[3][NM_TOT];       // 50MB bin-id cache (ws is 256MB)
};
#define ZBYTES (32 + CBLK*8)

// rotate-left via v_alignbit_b32 (single VALU op)
__device__ __forceinline__ uint32_t rotl(uint32_t x, uint32_t r) {
  return __builtin_amdgcn_alignbit(x, x, 32u - r);
}

// Threefry-2x32-20, matches JAX reference implementation exactly.
__device__ __forceinline__ void tf2(uint32_t k0, uint32_t k1,
                                    uint32_t& x0, uint32_t& x1) {
  uint32_t k2 = k0 ^ k1 ^ 0x1BD11BDAu;
  x0 += k0; x1 += k1;
#define QR(r) { x0 += x1; x1 = rotl(x1, r); x1 ^= x0; }
  QR(13) QR(15) QR(26) QR(6)  x0 += k1; x1 += k2 + 1u;
  QR(17) QR(29) QR(16) QR(24) x0 += k2; x1 += k0 + 2u;
  QR(13) QR(15) QR(26) QR(6)  x0 += k0; x1 += k1 + 3u;
  QR(17) QR(29) QR(16) QR(24) x0 += k1; x1 += k2 + 4u;
  QR(13) QR(15) QR(26) QR(6)  x0 += k2; x1 += k0 + 5u;
#undef QR
}

__device__ __forceinline__ uint32_t tf_bits(uint32_t k0, uint32_t k1, uint32_t p) {
  uint32_t a = 0u, b = p;
  tf2(k0, k1, a, b);
  return a ^ b;
}

__device__ __forceinline__ ull umax64(ull a, ull b) { return a > b ? a : b; }

// IoU mask + per-column argmax. Lane l owns column l; 8-row register
// prefetch amortizes LDS latency; 1024-thread blocks = 4 waves/SIMD.
// Last-done block reduces per-block partials and applies the "need" fixup.
__global__ __launch_bounds__(1024) void k_iou(const float4* __restrict__ pred,
                                              const float4* __restrict__ tgtb,
                                              WS* ws) {
  __shared__ float4 sp[1024];
  __shared__ ull cb[NBOXK];
  __shared__ ull red2[16][NBOXK];
  __shared__ uint32_t lastF;
  int t = threadIdx.x;
  int lane = t & 63;
  int w = t >> 6;
  int rowBase = blockIdx.x * 1024;
  sp[t] = pred[rowBase + t];
  if (t < NBOXK) cb[t] = 0ull;
  float4 tb = tgtb[lane];
  float ta = __fmul_rn(__fsub_rn(tb.z, tb.x), __fsub_rn(tb.w, tb.y));
  __syncthreads();
  ull myWord = 0ull;
  float bestI = -1.0f;
  uint32_t bestRow = 0u;
  int wbase = w * 64;
  for (int r0 = 0; r0 < 64; r0 += 8) {
    float4 pr[8];
#pragma unroll
    for (int e = 0; e < 8; ++e) pr[e] = sp[wbase + r0 + e];
#pragma unroll
    for (int e = 0; e < 8; ++e) {
      float4 p = pr[e];
      float pa = __fmul_rn(__fsub_rn(p.z, p.x), __fsub_rn(p.w, p.y));
      float ltx = fmaxf(p.x, tb.x), lty = fmaxf(p.y, tb.y);
      float rbx = fminf(p.z, tb.z), rby = fminf(p.w, tb.w);
      float wx = fmaxf(__fsub_rn(rbx, ltx), 0.0f);
      float wy = fmaxf(__fsub_rn(rby, lty), 0.0f);
      float inter = __fmul_rn(wx, wy);
      float uni = __fsub_rn(__fadd_rn(pa, ta), inter);
      float iou = __fdiv_rn(inter, uni);
      ull bal = __ballot(iou > 0.7f);
      if (lane == (r0 + e)) myWord = bal;
      if (iou > bestI) { bestI = iou; bestRow = (uint32_t)(rowBase + wbase + r0 + e); }
    }
  }
  ws->maskWords[rowBase + wbase + lane] = myWord;
  ull pk = ((ull)__float_as_uint(bestI) << 32) | (ull)(~bestRow);
  atomicMax(&cb[lane], pk);
  __syncthreads();                    // drains every wave's global stores
  if (t < NBOXK) ws->colBestBlk[blockIdx.x][t] = cb[t];
  if (t == 0) {
    __threadfence();                  // one wbl2 per block (covers block's L2 lines)
    lastF = (atomicAdd(&ws->iouDone, 1u) == (uint32_t)(gridDim.x - 1)) ? 1u : 0u;
  }
  __syncthreads();
  if (lastF) {
    __threadfence();                  // acquire
    int c = t & 63, q = t >> 6;       // q in 0..15
    ull best = 0ull;
    for (int b = q; b < IBLK; b += 16) best = umax64(best, ws->colBestBlk[b][c]);
    red2[q][c] = best;
    __syncthreads();
    if (t < NBOXK) {
      ull m_ = red2[0][t];
#pragma unroll
      for (int q2 = 1; q2 < 16; ++q2) m_ = umax64(m_, red2[q2][t]);
      float bi = __uint_as_float((uint32_t)(m_ >> 32));
      if (!(bi > 0.7f)) {
        uint32_t row = ~(uint32_t)(m_ & 0xFFFFFFFFu);
        atomicOr(&ws->maskWords[row], 1ull << t);
      }
    }
  }
}

// Fused count + global scan (windowed wave-parallel lookback) + ordered emit;
// block 511 does the scalar/PRNG setup.
__global__ __launch_bounds__(256) void k_scan_emit(WS* ws) {
  __shared__ uint32_t sm[256];
  __shared__ uint32_t exclS;
  int t = threadIdx.x, b = blockIdx.x;
  int row = b * 256 + t;
  ull w = ws->maskWords[row];
  uint32_t c = (uint32_t)__popcll(w);
  sm[t] = c;
  __syncthreads();
  for (int off = 1; off < 256; off <<= 1) {
    uint32_t add = (t >= off) ? sm[t - off] : 0u;
    __syncthreads();
    sm[t] += add;
    __syncthreads();
  }
  uint32_t mySum = sm[255];
  if (t == 0) {
    if (b == 0) {
      atomicExch(&ws->lookback[0], (2ull << 32) | (ull)mySum);
      exclS = 0u;
    } else {
      atomicExch(&ws->lookback[b], (1ull << 32) | (ull)mySum);
    }
    __threadfence();
  }
  if (b > 0 && t < 64) {
    int i = b - 1;
    uint32_t run = 0u;
    while (true) {
      int idx = i - t;
      ull x = (idx >= 0) ? atomicAdd(&ws->lookback[idx], 0ull) : (2ull << 32);
      uint32_t st = (uint32_t)(x >> 32);
      ull b2 = __ballot(st == 2u);
      ull b0 = __ballot(st == 0u);
      int f2 = (b2 == 0ull) ? 64 : (__ffsll((long long)b2) - 1);
      int f0 = (b0 == 0ull) ? 64 : (__ffsll((long long)b0) - 1);
      if (f0 < f2) continue;
      uint32_t v = (t <= f2) ? (uint32_t)x : 0u;
#pragma unroll
      for (int o = 32; o > 0; o >>= 1) v += __shfl_xor(v, o, 64);
      run += v;
      if (f2 < 64) break;
      i -= 64;
    }
    if (t == 0) {
      atomicExch(&ws->lookback[b], (2ull << 32) | (ull)(run + mySum));
      exclS = run;
    }
  }
  __syncthreads();
  uint32_t off0 = exclS + sm[t] - c;
  while (w) {
    int bit = __ffsll((long long)w) - 1;
    w &= (w - 1);
    if (off0 < TCAP) ws->T[off0] = ((uint32_t)row << 6) | (uint32_t)bit;
    off0++;
  }
  if (b == CBLK - 1) {
    ws->tgt[0][t] = (uint32_t)t;
    ws->tgt[1][t] = (uint32_t)t;
    if (t == 0) {
      uint32_t total = exclS + mySum;
      uint32_t P = total < (uint32_t)TCAP ? total : (uint32_t)TCAP;
      uint32_t M = NM_TOT - P;
      uint32_t npos = P < 128u ? P : 128u;
      ws->P = P; ws->M = M;
      ws->n_pos = npos; ws->n_neg = 256u - npos;
      ws->S[0] = P; ws->S[1] = M;
      ws->kcnt[0] = npos; ws->kcnt[1] = 256u - npos;
      const double LOGU = 22.18070977791825;  // log(2^32 - 1)
      for (int d = 0; d < 2; ++d) {
        uint32_t Sd = ws->S[d];
        int R = 0;
        if (Sd > 1u) {
          R = (int)ceil(3.0 * log((double)Sd) / LOGU);
          if (R < 1) R = 1;
          if (R > 3) R = 3;
        }
        ws->R[d] = (uint32_t)R;
        uint32_t ck0, ck1;
        { uint32_t a = 0u, bb = (uint32_t)d; tf2(0u, 42u, a, bb); ck0 = a; ck1 = bb; }
        for (int rr = 0; rr < 3; ++rr) {
          uint32_t s0 = 0u, s1 = 1u; tf2(ck0, ck1, s0, s1);
          ws->sub[d][rr][0] = s0; ws->sub[d][rr][1] = s1;
          uint32_t n0 = 0u, n1 = 0u; tf2(ck0, ck1, n0, n1);
          ck0 = n0; ck1 = n1;
        }
      }
    }
  }
}

// All 3 neg-round hists + bin-id caches. 16KB LDS (packed u16-pair), plain
// slice flush to hist3Blk (no global atomics). 512 blocks = 2 blk/CU.
__global__ __launch_bounds__(1024) void k_histA(WS* ws) {
  __shared__ uint32_t lh[4096];
  const uint32_t M = ws->M;
  uint32_t nquad = M >> 2, tail = M & 3u;
  uint32_t gtid = blockIdx.x * 1024u + threadIdx.x;
  const uint32_t stride = (uint32_t)HBLK * 1024u;
  for (int mm = 0; mm < 3; ++mm) {
    uint32_t sk0 = ws->sub[1][2 - mm][0], sk1 = ws->sub[1][2 - mm][1];
    uint16_t* bid = ws->binid3[mm];
    for (int i = threadIdx.x; i < 4096; i += 1024) lh[i] = 0u;
    __syncthreads();
    for (uint32_t q = gtid; q < nquad; q += stride) {
      uint32_t j = q << 2;
      uint32_t k0 = tf_bits(sk0, sk1, j);
      uint32_t k1 = tf_bits(sk0, sk1, j + 1);
      uint32_t k2 = tf_bits(sk0, sk1, j + 2);
      uint32_t k3 = tf_bits(sk0, sk1, j + 3);
      uint32_t b0 = k0 >> BINSHIFT, b1 = k1 >> BINSHIFT;
      uint32_t b2 = k2 >> BINSHIFT, b3 = k3 >> BINSHIFT;
      *(ull*)(bid + j) = (ull)b0 | ((ull)b1 << 16) | ((ull)b2 << 32) | ((ull)b3 << 48);
      atomicAdd(&lh[b0 >> 1], (b0 & 1) ? 0x10000u : 1u);
      atomicAdd(&lh[b1 >> 1], (b1 & 1) ? 0x10000u : 1u);
      atomicAdd(&lh[b2 >> 1], (b2 & 1) ? 0x10000u : 1u);
      atomicAdd(&lh[b3 >> 1], (b3 & 1) ? 0x10000u : 1u);
    }
    if (gtid < tail) {
      uint32_t j = (nquad << 2) + gtid;
      uint32_t k0 = tf_bits(sk0, sk1, j);
      uint32_t b0 = k0 >> BINSHIFT;
      bid[j] = (uint16_t)b0;
      atomicAdd(&lh[b0 >> 1], (b0 & 1) ? 0x10000u : 1u);
    }
    __syncthreads();
    for (int i = threadIdx.x; i < 4096; i += 1024)
      ws->hist3Blk[mm][blockIdx.x][i] = lh[i];
    __syncthreads();
  }
}

// scanloc body (1024 threads): LDS scan of hist3[m], per-target binary
// search, LDS bin dedup; writes binslot map + zeroes slotCnt/nslots.
__device__ void scanloc_body(WS* ws, int m, uint32_t* cumS, uint32_t* part,
                             int32_t* bslL, uint32_t* nslL) {
  int t = threadIdx.x;
  const int E = NBINS / 1024;
  uint32_t lv[E];
  uint32_t s = 0;
  uint32_t base = (uint32_t)t * E;
#pragma unroll
  for (int e = 0; e < E; ++e) { lv[e] = ws->hist3[m][base + e]; s += lv[e]; }
  part[t] = s;
  for (int i = t; i < NBINS; i += 1024) bslL[i] = -1;
  if (t == 0) *nslL = 0u;
  __syncthreads();
  for (int off = 1; off < 1024; off <<= 1) {
    uint32_t add = (t >= off) ? part[t - off] : 0u;
    __syncthreads();
    part[t] += add;
    __syncthreads();
  }
  uint32_t run = part[t] - s;
#pragma unroll
  for (int e = 0; e < E; ++e) { cumS[base + e] = run; run += lv[e]; }
  if (t == 1023) cumS[NBINS] = run;
  __syncthreads();
  uint32_t k = ws->kcnt[1];
  uint32_t lo = 0; int old = 0;
  if (t < (int)k) {
    uint32_t tr = ws->tgt[1][t];
    uint32_t hi = NBINS;
    while (hi - lo > 1u) {
      uint32_t mid = (lo + hi) >> 1;
      if (cumS[mid] <= tr) lo = mid; else hi = mid;
    }
    ws->tlocal[t] = tr - cumS[lo];
    old = atomicCAS(&bslL[lo], -1, (int)(0x10000u + (uint32_t)t));
  }
  __syncthreads();
  if (t < (int)k && old == -1) {
    uint32_t sl = atomicAdd(nslL, 1u);
    bslL[lo] = (int)sl;
  }
  __syncthreads();
  if (t < (int)k) ws->tslot[t] = (uint32_t)bslL[lo];
  for (int i = t; i < NBINS; i += 1024) ws->binslot[i] = bslL[i];
  if (t < MAXSLOT) ws->slotCnt[t] = 0u;
  if (t == 0) ws->nslots = *nslL;
}

union RedU {
  struct { uint32_t plo[4][256], phi[4][256]; } red;                  // 8KB
  struct { uint32_t cumS[NBINS + 1]; uint32_t part[1024];
           int32_t bsl[NBINS]; uint32_t nsl; } scan;                  // 68KB
  struct { uint32_t h8[NBINS]; uint32_t part[1024]; int32_t bsl[NBINS];
           ull sbuf[128][POSCAP]; uint32_t scntL[128];
           uint32_t tg[256], tlo[256], tsl[256]; uint32_t nsl; } pos; // 104KB
};

// blocks 0..47: coalesced reduce hist3Blk -> hist3; last-done block runs
// scanloc round 0. Block 48: whole pos chain. 49 blocks, co-resident.
__global__ __launch_bounds__(1024) void k_redscan(WS* ws) {
  __shared__ RedU su;
  __shared__ uint32_t lastF;
  int b = blockIdx.x, t = threadIdx.x;

  if (b == HRED) {
    // ---------------- pos chain ----------------
    int R = (int)ws->R[0];
    uint32_t P = ws->P;
    uint32_t k = ws->kcnt[0];
    if (R < 1) return;
    if (t < 256) su.pos.tg[t] = (uint32_t)t;
    __syncthreads();
    for (int r = R; r >= 1; --r) {
      uint32_t sk0 = ws->sub[0][r - 1][0], sk1 = ws->sub[0][r - 1][1];
      for (int i = t; i < NBINS; i += 1024) su.pos.h8[i] = 0u;
      __syncthreads();
      for (uint32_t j = t; j < P; j += 1024)
        atomicAdd(&su.pos.h8[tf_bits(sk0, sk1, j) >> BINSHIFT], 1u);
      __syncthreads();
      uint32_t lv[NBINS / 1024];
      uint32_t s = 0;
      uint32_t base = (uint32_t)t * (NBINS / 1024);
#pragma unroll
      for (int e = 0; e < NBINS / 1024; ++e) { lv[e] = su.pos.h8[base + e]; s += lv[e]; }
      su.pos.part[t] = s;
      __syncthreads();
      for (int off = 1; off < 1024; off <<= 1) {
        uint32_t add = (t >= off) ? su.pos.part[t - off] : 0u;
        __syncthreads();
        su.pos.part[t] += add;
        __syncthreads();
      }
      uint32_t run = su.pos.part[t] - s;
#pragma unroll
      for (int e = 0; e < NBINS / 1024; ++e) { su.pos.h8[base + e] = run; run += lv[e]; }
      for (int i = t; i < NBINS; i += 1024) su.pos.bsl[i] = -1;
      if (t == 0) su.pos.nsl = 0u;
      if (t < 128) su.pos.scntL[t] = 0u;
      __syncthreads();
      uint32_t lo = 0; int old = 0;
      if (t < (int)k) {
        uint32_t tr = su.pos.tg[t];
        uint32_t hi = NBINS;
        while (hi - lo > 1u) {
          uint32_t mid = (lo + hi) >> 1;
          if (su.pos.h8[mid] <= tr) lo = mid; else hi = mid;
        }
        su.pos.tlo[t] = tr - su.pos.h8[lo];
        old = atomicCAS(&su.pos.bsl[lo], -1, (int)(0x10000u + (uint32_t)t));
      }
      __syncthreads();
      if (t < (int)k && old == -1) {
        uint32_t sl = atomicAdd(&su.pos.nsl, 1u);
        su.pos.bsl[lo] = (int)sl;
      }
      __syncthreads();
      if (t < (int)k) su.pos.tsl[t] = (uint32_t)su.pos.bsl[lo];
      __syncthreads();
      for (uint32_t j = t; j < P; j += 1024) {
        uint32_t kk = tf_bits(sk0, sk1, j);
        int sl = su.pos.bsl[kk >> BINSHIFT];
        if (sl >= 0) {
          uint32_t idx = atomicAdd(&su.pos.scntL[sl], 1u);
          if (idx < POSCAP) su.pos.sbuf[sl][idx] = ((ull)kk << 24) | (ull)j;
        }
      }
      __syncthreads();
      if (t < (int)k) {
        uint32_t sl = su.pos.tsl[t], r2 = su.pos.tlo[t];
        uint32_t cn = su.pos.scntL[sl] < POSCAP ? su.pos.scntL[sl] : POSCAP;
        for (uint32_t x = 0; x < cn; ++x) {
          ull vx = su.pos.sbuf[sl][x];
          uint32_t rank = 0;
          for (uint32_t y = 0; y < cn; ++y) rank += (su.pos.sbuf[sl][y] < vx) ? 1u : 0u;
          if (rank == r2) { su.pos.tg[t] = (uint32_t)(vx & 0xFFFFFFull); break; }
        }
      }
      __syncthreads();
    }
    if (t < (int)k) ws->tgt[0][t] = su.pos.tg[t];
    return;
  }

  // ---------------- reducers (blocks 0..47) ----------------
  {
    uint32_t c = (uint32_t)b * 256u + ((uint32_t)t & 255u);
    uint32_t m_ = c >> 12, i_ = c & 4095u;
    uint32_t p = (uint32_t)t >> 8;
    uint32_t lo = 0u, hi = 0u;
    for (uint32_t blk = p; blk < (uint32_t)HBLK; blk += 4u) {
      uint32_t v = ws->hist3Blk[m_][blk][i_];
      lo += v & 0xFFFFu; hi += v >> 16;
    }
    su.red.plo[p][t & 255] = lo;
    su.red.phi[p][t & 255] = hi;
  }
  __syncthreads();
  if (t < 256) {
    uint32_t l2 = su.red.plo[0][t] + su.red.plo[1][t] + su.red.plo[2][t] + su.red.plo[3][t];
    uint32_t h2 = su.red.phi[0][t] + su.red.phi[1][t] + su.red.phi[2][t] + su.red.phi[3][t];
    uint32_t cc = (uint32_t)b * 256u + (uint32_t)t;
    uint32_t mm = cc >> 12, ii = cc & 4095u;
    ws->hist3[mm][2 * ii]     = l2;
    ws->hist3[mm][2 * ii + 1] = h2;
  }
  __syncthreads();                    // drain all waves' hist3 stores
  if (t == 0) {
    __threadfence();                  // single wbl2 per block
    lastF = (atomicAdd(&ws->redDone, 1u) == (uint32_t)(HRED - 1)) ? 1u : 0u;
  }
  __syncthreads();
  if (lastF) {
    __threadfence();
    scanloc_body(ws, 0, su.scan.cumS, su.scan.part, su.scan.bsl, &su.scan.nsl);
  }
}

// binid scanned as u64 quads -> LDS compaction -> threefry for hits only ->
// range-reserved slotBuf writes.
__global__ __launch_bounds__(1024) void k_gather(WS* ws, int m) {
  __shared__ int bs[NBINS];
  __shared__ uint32_t hk[HCAP];
  __shared__ uint32_t hj[HCAP];
  __shared__ uint32_t scnt[MAXSLOT];
  __shared__ uint32_t sbase_[MAXSLOT];
  __shared__ uint32_t scur[MAXSLOT];
  __shared__ uint32_t hcnt;
  int t = threadIdx.x;
  for (int i = t; i < NBINS; i += blockDim.x) bs[i] = ws->binslot[i];
  if (t < MAXSLOT) scnt[t] = 0u;
  if (t == 0) hcnt = 0u;
  __syncthreads();
  uint32_t S = ws->M;
  uint32_t sk0 = ws->sub[1][2 - m][0], sk1 = ws->sub[1][2 - m][1];
  const uint16_t* bid = ws->binid3[m];
  const ull* bid4 = (const ull*)bid;
  uint32_t nquad = S >> 2, tail = S & 3u;
  uint32_t gtid = blockIdx.x * blockDim.x + t;
  uint32_t stride = gridDim.x * blockDim.x;
  for (uint32_t q = gtid; q < nquad; q += stride) {
    ull v4 = bid4[q];
    uint32_t j0 = q << 2;
#pragma unroll
    for (int e = 0; e < 4; ++e) {
      uint32_t bb = (uint32_t)(v4 >> (16 * e)) & 0xFFFFu;
      int sl = bs[bb];
      if (sl >= 0) {
        uint32_t h = atomicAdd(&hcnt, 1u);
        if (h < HCAP) {
          hj[h] = j0 + (uint32_t)e;
        } else {
          uint32_t kk = tf_bits(sk0, sk1, j0 + (uint32_t)e);
          uint32_t idx = atomicAdd(&ws->slotCnt[sl], 1u);
          if (idx < SLOTCAP) ws->slotBuf[sl][idx] = ((ull)kk << 24) | (ull)(j0 + e);
        }
      }
    }
  }
  if (gtid < tail) {
    uint32_t j = (nquad << 2) + gtid;
    int sl = bs[bid[j]];
    if (sl >= 0) {
      uint32_t h = atomicAdd(&hcnt, 1u);
      if (h < HCAP) {
        hj[h] = j;
      } else {
        uint32_t kk = tf_bits(sk0, sk1, j);
        uint32_t idx = atomicAdd(&ws->slotCnt[sl], 1u);
        if (idx < SLOTCAP) ws->slotBuf[sl][idx] = ((ull)kk << 24) | (ull)j;
      }
    }
  }
  __syncthreads();
  uint32_t n = hcnt < (uint32_t)HCAP ? hcnt : (uint32_t)HCAP;
  for (uint32_t h = t; h < n; h += blockDim.x) {
    uint32_t kk = tf_bits(sk0, sk1, hj[h]);
    hk[h] = kk;
    atomicAdd(&scnt[bs[kk >> BINSHIFT]], 1u);
  }
  __syncthreads();
  if (t < MAXSLOT) {
    scur[t] = 0u;
    if (scnt[t]) sbase_[t] = atomicAdd(&ws->slotCnt[t], scnt[t]);
  }
  __syncthreads();
  for (uint32_t h = t; h < n; h += blockDim.x) {
    uint32_t kk = hk[h], j = hj[h];
    int sl = bs[kk >> BINSHIFT];
    uint32_t idx = sbase_[sl] + atomicAdd(&scur[sl], 1u);
    if (idx < SLOTCAP) ws->slotBuf[sl][idx] = ((ull)kk << 24) | (ull)j;
  }
}

// Counting-sort select for slot=blockIdx.x; if doNext, last-finishing block
// runs scanloc for round m+1 (t0-only release fence).
__global__ __launch_bounds__(1024) void k_selscan(WS* ws, int m, int doNext) {
  __shared__ ull      srt[SLOTCAP];
  __shared__ uint32_t hh[256];
  __shared__ uint32_t cum[257];
  __shared__ uint32_t cur[256];
  __shared__ uint32_t sb[256];
  __shared__ uint32_t cumS[NBINS + 1];
  __shared__ uint32_t part[1024];
  __shared__ int32_t  bslL[NBINS];
  __shared__ uint32_t nslL;
  __shared__ uint32_t lastF;
  int t = threadIdx.x;
  int slot = blockIdx.x;
  uint32_t nslots = ws->nslots;
  if ((uint32_t)slot < nslots) {
    uint32_t cnt = ws->slotCnt[slot];
    if (cnt > SLOTCAP) cnt = SLOTCAP;
    if (t < 256) hh[t] = 0u;
    __syncthreads();
    for (uint32_t i = t; i < cnt; i += 1024) {
      ull v = ws->slotBuf[slot][i];
      atomicAdd(&hh[(uint32_t)(v >> 35) & 255u], 1u);
    }
    __syncthreads();
    if (t < 256) sb[t] = hh[t];
    __syncthreads();
    for (int off = 1; off < 256; off <<= 1) {
      uint32_t add = (t >= off && t < 256) ? sb[t - off] : 0u;
      __syncthreads();
      if (t < 256) sb[t] += add;
      __syncthreads();
    }
    if (t == 0) cum[0] = 0u;
    if (t < 256) { cum[t + 1] = sb[t]; cur[t] = 0u; }
    __syncthreads();
    for (uint32_t i = t; i < cnt; i += 1024) {
      ull v = ws->slotBuf[slot][i];
      uint32_t bb = (uint32_t)(v >> 35) & 255u;
      uint32_t idx = cum[bb] + atomicAdd(&cur[bb], 1u);
      srt[idx] = v;
    }
    __syncthreads();
    uint32_t k = ws->kcnt[1];
    if (t < (int)k && ws->tslot[t] == (uint32_t)slot) {
      uint32_t tr = ws->tlocal[t];
      uint32_t lo = 0, hi = 256;
      while (hi - lo > 1u) {
        uint32_t mid = (lo + hi) >> 1;
        if (cum[mid] <= tr) lo = mid; else hi = mid;
      }
      uint32_t r2 = tr - cum[lo];
      uint32_t b0 = cum[lo], b1 = cum[lo + 1];
      for (uint32_t x = b0; x < b1; ++x) {
        ull vx = srt[x];
        uint32_t rank = 0;
        for (uint32_t y = b0; y < b1; ++y) rank += (srt[y] < vx) ? 1u : 0u;
        if (rank == r2) { ws->tgt[1][t] = (uint32_t)(vx & 0xFFFFFFull); break; }
      }
    }
  }
  if (doNext) {
    __syncthreads();                  // drain all waves' tgt stores
    if (t == 0) {
      __threadfence();                // single wbl2 per block
      lastF = (atomicAdd(&ws->selDone[m], 1u) == (uint32_t)(gridDim.x - 1)) ? 1u : 0u;
    }
    __syncthreads();
    if (lastF) {
      __threadfence();
      scanloc_body(ws, m + 1, cumS, part, bslL, &nslL);
    }
  }
}

__device__ __forceinline__ float sl1(float dd) {
  float ad = fabsf(dd);
  return (ad < 1.0f) ? 0.5f * dd * dd : ad - 0.5f;
}

__global__ __launch_bounds__(256) void k_loss(WS* ws,
                                              const float* __restrict__ reg,
                                              const float* __restrict__ obj,
                                              const float4* __restrict__ tgtb,
                                              const float4* __restrict__ anch,
                                              float* out) {
  int s = threadIdx.x;
  uint32_t npos = ws->n_pos;
  double lr = 0.0, bc = 0.0;
  if (s < (int)npos) {
    uint32_t v = ws->tgt[0][s];
    uint32_t pa = ws->T[v];
    uint32_t i = pa >> 6, j = pa & 63u;
    float4 t = tgtb[j];
    float tcx = (t.x + t.z) * 0.5f, tcy = (t.y + t.w) * 0.5f;
    float tw = t.z - t.x, th = t.w - t.y;
    float4 a = anch[i];
    float r0 = (tcx - a.x) / a.z;
    float r1 = (tcy - a.y) / a.w;
    float r2 = logf(tw / a.z);
    float r3 = logf(th / a.w);
    lr = (double)sl1(reg[i * 4 + 0] - r0) + (double)sl1(reg[i * 4 + 1] - r1) +
         (double)sl1(reg[i * 4 + 2] - r2) + (double)sl1(reg[i * 4 + 3] - r3);
    float x = obj[i];
    bc = (double)(fmaxf(x, 0.0f) - x + log1pf(expf(-fabsf(x))));
  } else {
    uint32_t e = ws->tgt[1][s - (int)npos];
    uint32_t P = ws->P;
    uint32_t lo = 0, hi = P;
    while (lo < hi) {
      uint32_t mid = (lo + hi) >> 1;
      if (ws->T[mid] - mid > e) hi = mid; else lo = mid + 1;
    }
    uint32_t f = e + lo;
    uint32_t i = f >> 6;
    float x = obj[i];
    bc = (double)(fmaxf(x, 0.0f) + log1pf(expf(-fabsf(x))));
  }
  __shared__ double sA[256], sB[256];
  sA[s] = lr; sB[s] = bc;
  __syncthreads();
  for (int off = 128; off > 0; off >>= 1) {
    if (s < off) { sA[s] += sA[s + off]; sB[s] += sB[s + off]; }
    __syncthreads();
  }
  if (s == 0)
    out[0] = (float)(sA[0] * (10.0 / 2500.0) + sB[0] * (1.0 / 256.0));
}

extern "C" void kernel_launch(void* const* d_in, const int* in_sizes, int n_in,
                              void* d_out, int out_size, void* d_ws,
                              size_t ws_size, hipStream_t stream) {
  const float*  reg  = (const float*)d_in[0];
  const float*  obj  = (const float*)d_in[1];
  const float4* pred = (const float4*)d_in[2];
  const float4* tgtb = (const float4*)d_in[3];
  const float4* anch = (const float4*)d_in[4];
  float* out = (float*)d_out;
  WS* ws = (WS*)d_ws;
  (void)in_sizes; (void)n_in; (void)out_size; (void)ws_size;

  hipMemsetAsync(d_ws, 0, ZBYTES, stream);   // ctrl counters + lookback
  k_iou<<<IBLK, 1024, 0, stream>>>(pred, tgtb, ws);
  k_scan_emit<<<CBLK, 256, 0, stream>>>(ws);
  k_histA<<<HBLK, 1024, 0, stream>>>(ws);
  k_redscan<<<HRED + 1, 1024, 0, stream>>>(ws);  // reduce + scanloc0 + pos
  for (int m = 0; m < 3; ++m) {
    k_gather<<<CBLK, 1024, 0, stream>>>(ws, m);
    k_selscan<<<MAXSLOT, 1024, 0, stream>>>(ws, m, (m < 2) ? 1 : 0);
  }
  k_loss<<<1, 256, 0, stream>>>(ws, reg, obj, tgtb, anch, out);
}

// Round 14
// 226.417 us; speedup vs baseline: 2.0371x; 1.0567x over previous
//
#include <hip/hip_runtime.h>
#include <stdint.h>

// ---------------------------------------------------------------------------
// RPN loss: IoU>0.7 matching + argmax fix + exact JAX threefry sampling
// (partitionable PRNG path) + smooth-L1 + BCE, all on device.
// R1-R7: algorithmic fixes (2785 -> 314us). R8-R13: launch collapse, fence
// repair, occupancy repair (239us).
// R14: k_histA merges all 3 hist rounds into ONE scan pass (12 indep threefry
// chains/iter, lh[3][4096]=48KB, one clear+flush, 2 barriers) — amortizes the
// ~2x loop/flush overhead over the 26us threefry VALU floor. k_loss fused
// into k_selscan(m=2) last-done block (one fewer launch).
// ---------------------------------------------------------------------------

#define N_PRED   131072
#define NBOXK    64
#define NM_TOT   8388608u          // N_PRED * NBOXK
#define TCAP     65536
#define NBINS    8192
#define BINSHIFT 19                // key >> 19 -> 13-bit bin
#define SLOTCAP  3072
#define MAXSLOT  192
#define HCAP     2048              // per-block LDS hit buffer (gather)
#define CBLK     512               // scan blocks
#define IBLK     128               // iou blocks (1024 thr each)
#define POSCAP   32                // per-bin candidate cap in pos chain
#define HBLK     512               // hist worker blocks
#define HRED     48                // reducer blocks in k_redscan

typedef unsigned long long ull;

struct WS {
  // ---- zeroed by hipMemsetAsync at the head of every launch ----
  uint32_t iouDone, redDone, selDone[3], zpad[3];             // 32B
  ull      lookback[CBLK];                                    // 4KB
  // ---- end zero region (ZBYTES) ----
  uint32_t P, M, n_pos, n_neg;
  uint32_t R[2], S[2], kcnt[2];
  uint32_t sub[2][3][2];            // per-round subkeys
  uint32_t nslots;
  uint32_t hist3[3][NBINS];         // reduced hists (plain-written)
  ull      colBestBlk[IBLK][NBOXK]; // per-block iou argmax partials
  ull      maskWords[N_PRED];
  uint32_t T[TCAP];
  uint32_t tgt[2][256];
  int32_t  binslot[NBINS];
  int32_t  tslot[256];
  uint32_t tlocal[256];
  uint32_t slotCnt[MAXSLOT];
  ull      slotBuf[MAXSLOT][SLOTCAP];
  uint32_t hist3Blk[3][HBLK][4096]; // per-block u16-pair hist slices, 25MB
  uint16_t binid3[3][NM_TOT];       // 50MB bin-id cache (ws is 256MB)
};
#define ZBYTES (32 + CBLK*8)

// rotate-left via v_alignbit_b32 (single VALU op)
__device__ __forceinline__ uint32_t rotl(uint32_t x, uint32_t r) {
  return __builtin_amdgcn_alignbit(x, x, 32u - r);
}

// Threefry-2x32-20, matches JAX reference implementation exactly.
__device__ __forceinline__ void tf2(uint32_t k0, uint32_t k1,
                                    uint32_t& x0, uint32_t& x1) {
  uint32_t k2 = k0 ^ k1 ^ 0x1BD11BDAu;
  x0 += k0; x1 += k1;
#define QR(r) { x0 += x1; x1 = rotl(x1, r); x1 ^= x0; }
  QR(13) QR(15) QR(26) QR(6)  x0 += k1; x1 += k2 + 1u;
  QR(17) QR(29) QR(16) QR(24) x0 += k2; x1 += k0 + 2u;
  QR(13) QR(15) QR(26) QR(6)  x0 += k0; x1 += k1 + 3u;
  QR(17) QR(29) QR(16) QR(24) x0 += k1; x1 += k2 + 4u;
  QR(13) QR(15) QR(26) QR(6)  x0 += k2; x1 += k0 + 5u;
#undef QR
}

__device__ __forceinline__ uint32_t tf_bits(uint32_t k0, uint32_t k1, uint32_t p) {
  uint32_t a = 0u, b = p;
  tf2(k0, k1, a, b);
  return a ^ b;
}

__device__ __forceinline__ ull umax64(ull a, ull b) { return a > b ? a : b; }

// IoU mask + per-column argmax. Lane l owns column l; 8-row register
// prefetch; 1024-thread blocks; last-done block reduces + "need" fixup.
__global__ __launch_bounds__(1024) void k_iou(const float4* __restrict__ pred,
                                              const float4* __restrict__ tgtb,
                                              WS* ws) {
  __shared__ float4 sp[1024];
  __shared__ ull cb[NBOXK];
  __shared__ ull red2[16][NBOXK];
  __shared__ uint32_t lastF;
  int t = threadIdx.x;
  int lane = t & 63;
  int w = t >> 6;
  int rowBase = blockIdx.x * 1024;
  sp[t] = pred[rowBase + t];
  if (t < NBOXK) cb[t] = 0ull;
  float4 tb = tgtb[lane];
  float ta = __fmul_rn(__fsub_rn(tb.z, tb.x), __fsub_rn(tb.w, tb.y));
  __syncthreads();
  ull myWord = 0ull;
  float bestI = -1.0f;
  uint32_t bestRow = 0u;
  int wbase = w * 64;
  for (int r0 = 0; r0 < 64; r0 += 8) {
    float4 pr[8];
#pragma unroll
    for (int e = 0; e < 8; ++e) pr[e] = sp[wbase + r0 + e];
#pragma unroll
    for (int e = 0; e < 8; ++e) {
      float4 p = pr[e];
      float pa = __fmul_rn(__fsub_rn(p.z, p.x), __fsub_rn(p.w, p.y));
      float ltx = fmaxf(p.x, tb.x), lty = fmaxf(p.y, tb.y);
      float rbx = fminf(p.z, tb.z), rby = fminf(p.w, tb.w);
      float wx = fmaxf(__fsub_rn(rbx, ltx), 0.0f);
      float wy = fmaxf(__fsub_rn(rby, lty), 0.0f);
      float inter = __fmul_rn(wx, wy);
      float uni = __fsub_rn(__fadd_rn(pa, ta), inter);
      float iou = __fdiv_rn(inter, uni);
      ull bal = __ballot(iou > 0.7f);
      if (lane == (r0 + e)) myWord = bal;
      if (iou > bestI) { bestI = iou; bestRow = (uint32_t)(rowBase + wbase + r0 + e); }
    }
  }
  ws->maskWords[rowBase + wbase + lane] = myWord;
  ull pk = ((ull)__float_as_uint(bestI) << 32) | (ull)(~bestRow);
  atomicMax(&cb[lane], pk);
  __syncthreads();
  if (t < NBOXK) ws->colBestBlk[blockIdx.x][t] = cb[t];
  if (t == 0) {
    __threadfence();                  // one wbl2 per block
    lastF = (atomicAdd(&ws->iouDone, 1u) == (uint32_t)(gridDim.x - 1)) ? 1u : 0u;
  }
  __syncthreads();
  if (lastF) {
    __threadfence();
    int c = t & 63, q = t >> 6;
    ull best = 0ull;
    for (int b = q; b < IBLK; b += 16) best = umax64(best, ws->colBestBlk[b][c]);
    red2[q][c] = best;
    __syncthreads();
    if (t < NBOXK) {
      ull m_ = red2[0][t];
#pragma unroll
      for (int q2 = 1; q2 < 16; ++q2) m_ = umax64(m_, red2[q2][t]);
      float bi = __uint_as_float((uint32_t)(m_ >> 32));
      if (!(bi > 0.7f)) {
        uint32_t row = ~(uint32_t)(m_ & 0xFFFFFFFFu);
        atomicOr(&ws->maskWords[row], 1ull << t);
      }
    }
  }
}

// Fused count + global scan (windowed wave-parallel lookback) + ordered emit;
// block 511 does the scalar/PRNG setup.
__global__ __launch_bounds__(256) void k_scan_emit(WS* ws) {
  __shared__ uint32_t sm[256];
  __shared__ uint32_t exclS;
  int t = threadIdx.x, b = blockIdx.x;
  int row = b * 256 + t;
  ull w = ws->maskWords[row];
  uint32_t c = (uint32_t)__popcll(w);
  sm[t] = c;
  __syncthreads();
  for (int off = 1; off < 256; off <<= 1) {
    uint32_t add = (t >= off) ? sm[t - off] : 0u;
    __syncthreads();
    sm[t] += add;
    __syncthreads();
  }
  uint32_t mySum = sm[255];
  if (t == 0) {
    if (b == 0) {
      atomicExch(&ws->lookback[0], (2ull << 32) | (ull)mySum);
      exclS = 0u;
    } else {
      atomicExch(&ws->lookback[b], (1ull << 32) | (ull)mySum);
    }
    __threadfence();
  }
  if (b > 0 && t < 64) {
    int i = b - 1;
    uint32_t run = 0u;
    while (true) {
      int idx = i - t;
      ull x = (idx >= 0) ? atomicAdd(&ws->lookback[idx], 0ull) : (2ull << 32);
      uint32_t st = (uint32_t)(x >> 32);
      ull b2 = __ballot(st == 2u);
      ull b0 = __ballot(st == 0u);
      int f2 = (b2 == 0ull) ? 64 : (__ffsll((long long)b2) - 1);
      int f0 = (b0 == 0ull) ? 64 : (__ffsll((long long)b0) - 1);
      if (f0 < f2) continue;
      uint32_t v = (t <= f2) ? (uint32_t)x : 0u;
#pragma unroll
      for (int o = 32; o > 0; o >>= 1) v += __shfl_xor(v, o, 64);
      run += v;
      if (f2 < 64) break;
      i -= 64;
    }
    if (t == 0) {
      atomicExch(&ws->lookback[b], (2ull << 32) | (ull)(run + mySum));
      exclS = run;
    }
  }
  __syncthreads();
  uint32_t off0 = exclS + sm[t] - c;
  while (w) {
    int bit = __ffsll((long long)w) - 1;
    w &= (w - 1);
    if (off0 < TCAP) ws->T[off0] = ((uint32_t)row << 6) | (uint32_t)bit;
    off0++;
  }
  if (b == CBLK - 1) {
    ws->tgt[0][t] = (uint32_t)t;
    ws->tgt[1][t] = (uint32_t)t;
    if (t == 0) {
      uint32_t total = exclS + mySum;
      uint32_t P = total < (uint32_t)TCAP ? total : (uint32_t)TCAP;
      uint32_t M = NM_TOT - P;
      uint32_t npos = P < 128u ? P : 128u;
      ws->P = P; ws->M = M;
      ws->n_pos = npos; ws->n_neg = 256u - npos;
      ws->S[0] = P; ws->S[1] = M;
      ws->kcnt[0] = npos; ws->kcnt[1] = 256u - npos;
      const double LOGU = 22.18070977791825;  // log(2^32 - 1)
      for (int d = 0; d < 2; ++d) {
        uint32_t Sd = ws->S[d];
        int R = 0;
        if (Sd > 1u) {
          R = (int)ceil(3.0 * log((double)Sd) / LOGU);
          if (R < 1) R = 1;
          if (R > 3) R = 3;
        }
        ws->R[d] = (uint32_t)R;
        uint32_t ck0, ck1;
        { uint32_t a = 0u, bb = (uint32_t)d; tf2(0u, 42u, a, bb); ck0 = a; ck1 = bb; }
        for (int rr = 0; rr < 3; ++rr) {
          uint32_t s0 = 0u, s1 = 1u; tf2(ck0, ck1, s0, s1);
          ws->sub[d][rr][0] = s0; ws->sub[d][rr][1] = s1;
          uint32_t n0 = 0u, n1 = 0u; tf2(ck0, ck1, n0, n1);
          ck0 = n0; ck1 = n1;
        }
      }
    }
  }
}

// All 3 neg-round hists + bin-id caches in ONE scan pass: 12 independent
// threefry chains per iteration, lh[3][4096] (48KB), one clear + one flush.
__global__ __launch_bounds__(1024) void k_histA(WS* ws) {
  __shared__ uint32_t lh[3][4096];   // 48KB -> still 2 blocks/CU
  const uint32_t M = ws->M;
  uint32_t nquad = M >> 2, tail = M & 3u;
  uint32_t gtid = blockIdx.x * 1024u + threadIdx.x;
  const uint32_t stride = (uint32_t)HBLK * 1024u;
  uint32_t sk0_0 = ws->sub[1][2][0], sk1_0 = ws->sub[1][2][1];
  uint32_t sk0_1 = ws->sub[1][1][0], sk1_1 = ws->sub[1][1][1];
  uint32_t sk0_2 = ws->sub[1][0][0], sk1_2 = ws->sub[1][0][1];
  for (int i = threadIdx.x; i < 3 * 4096; i += 1024) (&lh[0][0])[i] = 0u;
  __syncthreads();
  for (uint32_t q = gtid; q < nquad; q += stride) {
    uint32_t j = q << 2;
#define HQUAD(mm, K0, K1)                                                     \
    {                                                                         \
      uint32_t k0 = tf_bits(K0, K1, j);                                       \
      uint32_t k1 = tf_bits(K0, K1, j + 1);                                   \
      uint32_t k2 = tf_bits(K0, K1, j + 2);                                   \
      uint32_t k3 = tf_bits(K0, K1, j + 3);                                   \
      uint32_t b0 = k0 >> BINSHIFT, b1 = k1 >> BINSHIFT;                      \
      uint32_t b2 = k2 >> BINSHIFT, b3 = k3 >> BINSHIFT;                      \
      *(ull*)(ws->binid3[mm] + j) =                                           \
          (ull)b0 | ((ull)b1 << 16) | ((ull)b2 << 32) | ((ull)b3 << 48);      \
      atomicAdd(&lh[mm][b0 >> 1], (b0 & 1) ? 0x10000u : 1u);                  \
      atomicAdd(&lh[mm][b1 >> 1], (b1 & 1) ? 0x10000u : 1u);                  \
      atomicAdd(&lh[mm][b2 >> 1], (b2 & 1) ? 0x10000u : 1u);                  \
      atomicAdd(&lh[mm][b3 >> 1], (b3 & 1) ? 0x10000u : 1u);                  \
    }
    HQUAD(0, sk0_0, sk1_0)
    HQUAD(1, sk0_1, sk1_1)
    HQUAD(2, sk0_2, sk1_2)
#undef HQUAD
  }
  if (gtid < tail) {
    uint32_t j = (nquad << 2) + gtid;
#define HTAIL(mm, K0, K1)                                                     \
    {                                                                         \
      uint32_t k0 = tf_bits(K0, K1, j);                                       \
      uint32_t b0 = k0 >> BINSHIFT;                                           \
      ws->binid3[mm][j] = (uint16_t)b0;                                       \
      atomicAdd(&lh[mm][b0 >> 1], (b0 & 1) ? 0x10000u : 1u);                  \
    }
    HTAIL(0, sk0_0, sk1_0)
    HTAIL(1, sk0_1, sk1_1)
    HTAIL(2, sk0_2, sk1_2)
#undef HTAIL
  }
  __syncthreads();
  for (int i = threadIdx.x; i < 4096; i += 1024) {
    ws->hist3Blk[0][blockIdx.x][i] = lh[0][i];
    ws->hist3Blk[1][blockIdx.x][i] = lh[1][i];
    ws->hist3Blk[2][blockIdx.x][i] = lh[2][i];
  }
}

// scanloc body (1024 threads): LDS scan of hist3[m], per-target binary
// search, LDS bin dedup; writes binslot map + zeroes slotCnt/nslots.
__device__ void scanloc_body(WS* ws, int m, uint32_t* cumS, uint32_t* part,
                             int32_t* bslL, uint32_t* nslL) {
  int t = threadIdx.x;
  const int E = NBINS / 1024;
  uint32_t lv[E];
  uint32_t s = 0;
  uint32_t base = (uint32_t)t * E;
#pragma unroll
  for (int e = 0; e < E; ++e) { lv[e] = ws->hist3[m][base + e]; s += lv[e]; }
  part[t] = s;
  for (int i = t; i < NBINS; i += 1024) bslL[i] = -1;
  if (t == 0) *nslL = 0u;
  __syncthreads();
  for (int off = 1; off < 1024; off <<= 1) {
    uint32_t add = (t >= off) ? part[t - off] : 0u;
    __syncthreads();
    part[t] += add;
    __syncthreads();
  }
  uint32_t run = part[t] - s;
#pragma unroll
  for (int e = 0; e < E; ++e) { cumS[base + e] = run; run += lv[e]; }
  if (t == 1023) cumS[NBINS] = run;
  __syncthreads();
  uint32_t k = ws->kcnt[1];
  uint32_t lo = 0; int old = 0;
  if (t < (int)k) {
    uint32_t tr = ws->tgt[1][t];
    uint32_t hi = NBINS;
    while (hi - lo > 1u) {
      uint32_t mid = (lo + hi) >> 1;
      if (cumS[mid] <= tr) lo = mid; else hi = mid;
    }
    ws->tlocal[t] = tr - cumS[lo];
    old = atomicCAS(&bslL[lo], -1, (int)(0x10000u + (uint32_t)t));
  }
  __syncthreads();
  if (t < (int)k && old == -1) {
    uint32_t sl = atomicAdd(nslL, 1u);
    bslL[lo] = (int)sl;
  }
  __syncthreads();
  if (t < (int)k) ws->tslot[t] = (uint32_t)bslL[lo];
  for (int i = t; i < NBINS; i += 1024) ws->binslot[i] = bslL[i];
  if (t < MAXSLOT) ws->slotCnt[t] = 0u;
  if (t == 0) ws->nslots = *nslL;
}

union RedU {
  struct { uint32_t plo[4][256], phi[4][256]; } red;                  // 8KB
  struct { uint32_t cumS[NBINS + 1]; uint32_t part[1024];
           int32_t bsl[NBINS]; uint32_t nsl; } scan;                  // 68KB
  struct { uint32_t h8[NBINS]; uint32_t part[1024]; int32_t bsl[NBINS];
           ull sbuf[128][POSCAP]; uint32_t scntL[128];
           uint32_t tg[256], tlo[256], tsl[256]; uint32_t nsl; } pos; // 104KB
};

// blocks 0..47: coalesced reduce hist3Blk -> hist3; last-done block runs
// scanloc round 0. Block 48: whole pos chain. 49 blocks, co-resident.
__global__ __launch_bounds__(1024) void k_redscan(WS* ws) {
  __shared__ RedU su;
  __shared__ uint32_t lastF;
  int b = blockIdx.x, t = threadIdx.x;

  if (b == HRED) {
    int R = (int)ws->R[0];
    uint32_t P = ws->P;
    uint32_t k = ws->kcnt[0];
    if (R < 1) return;
    if (t < 256) su.pos.tg[t] = (uint32_t)t;
    __syncthreads();
    for (int r = R; r >= 1; --r) {
      uint32_t sk0 = ws->sub[0][r - 1][0], sk1 = ws->sub[0][r - 1][1];
      for (int i = t; i < NBINS; i += 1024) su.pos.h8[i] = 0u;
      __syncthreads();
      for (uint32_t j = t; j < P; j += 1024)
        atomicAdd(&su.pos.h8[tf_bits(sk0, sk1, j) >> BINSHIFT], 1u);
      __syncthreads();
      uint32_t lv[NBINS / 1024];
      uint32_t s = 0;
      uint32_t base = (uint32_t)t * (NBINS / 1024);
#pragma unroll
      for (int e = 0; e < NBINS / 1024; ++e) { lv[e] = su.pos.h8[base + e]; s += lv[e]; }
      su.pos.part[t] = s;
      __syncthreads();
      for (int off = 1; off < 1024; off <<= 1) {
        uint32_t add = (t >= off) ? su.pos.part[t - off] : 0u;
        __syncthreads();
        su.pos.part[t] += add;
        __syncthreads();
      }
      uint32_t run = su.pos.part[t] - s;
#pragma unroll
      for (int e = 0; e < NBINS / 1024; ++e) { su.pos.h8[base + e] = run; run += lv[e]; }
      for (int i = t; i < NBINS; i += 1024) su.pos.bsl[i] = -1;
      if (t == 0) su.pos.nsl = 0u;
      if (t < 128) su.pos.scntL[t] = 0u;
      __syncthreads();
      uint32_t lo = 0; int old = 0;
      if (t < (int)k) {
        uint32_t tr = su.pos.tg[t];
        uint32_t hi = NBINS;
        while (hi - lo > 1u) {
          uint32_t mid = (lo + hi) >> 1;
          if (su.pos.h8[mid] <= tr) lo = mid; else hi = mid;
        }
        su.pos.tlo[t] = tr - su.pos.h8[lo];
        old = atomicCAS(&su.pos.bsl[lo], -1, (int)(0x10000u + (uint32_t)t));
      }
      __syncthreads();
      if (t < (int)k && old == -1) {
        uint32_t sl = atomicAdd(&su.pos.nsl, 1u);
        su.pos.bsl[lo] = (int)sl;
      }
      __syncthreads();
      if (t < (int)k) su.pos.tsl[t] = (uint32_t)su.pos.bsl[lo];
      __syncthreads();
      for (uint32_t j = t; j < P; j += 1024) {
        uint32_t kk = tf_bits(sk0, sk1, j);
        int sl = su.pos.bsl[kk >> BINSHIFT];
        if (sl >= 0) {
          uint32_t idx = atomicAdd(&su.pos.scntL[sl], 1u);
          if (idx < POSCAP) su.pos.sbuf[sl][idx] = ((ull)kk << 24) | (ull)j;
        }
      }
      __syncthreads();
      if (t < (int)k) {
        uint32_t sl = su.pos.tsl[t], r2 = su.pos.tlo[t];
        uint32_t cn = su.pos.scntL[sl] < POSCAP ? su.pos.scntL[sl] : POSCAP;
        for (uint32_t x = 0; x < cn; ++x) {
          ull vx = su.pos.sbuf[sl][x];
          uint32_t rank = 0;
          for (uint32_t y = 0; y < cn; ++y) rank += (su.pos.sbuf[sl][y] < vx) ? 1u : 0u;
          if (rank == r2) { su.pos.tg[t] = (uint32_t)(vx & 0xFFFFFFull); break; }
        }
      }
      __syncthreads();
    }
    if (t < (int)k) ws->tgt[0][t] = su.pos.tg[t];
    return;
  }

  // reducers (blocks 0..47)
  {
    uint32_t c = (uint32_t)b * 256u + ((uint32_t)t & 255u);
    uint32_t m_ = c >> 12, i_ = c & 4095u;
    uint32_t p = (uint32_t)t >> 8;
    uint32_t lo = 0u, hi = 0u;
    for (uint32_t blk = p; blk < (uint32_t)HBLK; blk += 4u) {
      uint32_t v = ws->hist3Blk[m_][blk][i_];
      lo += v & 0xFFFFu; hi += v >> 16;
    }
    su.red.plo[p][t & 255] = lo;
    su.red.phi[p][t & 255] = hi;
  }
  __syncthreads();
  if (t < 256) {
    uint32_t l2 = su.red.plo[0][t] + su.red.plo[1][t] + su.red.plo[2][t] + su.red.plo[3][t];
    uint32_t h2 = su.red.phi[0][t] + su.red.phi[1][t] + su.red.phi[2][t] + su.red.phi[3][t];
    uint32_t cc = (uint32_t)b * 256u + (uint32_t)t;
    uint32_t mm = cc >> 12, ii = cc & 4095u;
    ws->hist3[mm][2 * ii]     = l2;
    ws->hist3[mm][2 * ii + 1] = h2;
  }
  __syncthreads();
  if (t == 0) {
    __threadfence();
    lastF = (atomicAdd(&ws->redDone, 1u) == (uint32_t)(HRED - 1)) ? 1u : 0u;
  }
  __syncthreads();
  if (lastF) {
    __threadfence();
    scanloc_body(ws, 0, su.scan.cumS, su.scan.part, su.scan.bsl, &su.scan.nsl);
  }
}

// binid scanned as u64 quads -> LDS compaction -> threefry for hits only ->
// range-reserved slotBuf writes.
__global__ __launch_bounds__(1024) void k_gather(WS* ws, int m) {
  __shared__ int bs[NBINS];
  __shared__ uint32_t hk[HCAP];
  __shared__ uint32_t hj[HCAP];
  __shared__ uint32_t scnt[MAXSLOT];
  __shared__ uint32_t sbase_[MAXSLOT];
  __shared__ uint32_t scur[MAXSLOT];
  __shared__ uint32_t hcnt;
  int t = threadIdx.x;
  for (int i = t; i < NBINS; i += blockDim.x) bs[i] = ws->binslot[i];
  if (t < MAXSLOT) scnt[t] = 0u;
  if (t == 0) hcnt = 0u;
  __syncthreads();
  uint32_t S = ws->M;
  uint32_t sk0 = ws->sub[1][2 - m][0], sk1 = ws->sub[1][2 - m][1];
  const uint16_t* bid = ws->binid3[m];
  const ull* bid4 = (const ull*)bid;
  uint32_t nquad = S >> 2, tail = S & 3u;
  uint32_t gtid = blockIdx.x * blockDim.x + t;
  uint32_t stride = gridDim.x * blockDim.x;
  for (uint32_t q = gtid; q < nquad; q += stride) {
    ull v4 = bid4[q];
    uint32_t j0 = q << 2;
#pragma unroll
    for (int e = 0; e < 4; ++e) {
      uint32_t bb = (uint32_t)(v4 >> (16 * e)) & 0xFFFFu;
      int sl = bs[bb];
      if (sl >= 0) {
        uint32_t h = atomicAdd(&hcnt, 1u);
        if (h < HCAP) {
          hj[h] = j0 + (uint32_t)e;
        } else {
          uint32_t kk = tf_bits(sk0, sk1, j0 + (uint32_t)e);
          uint32_t idx = atomicAdd(&ws->slotCnt[sl], 1u);
          if (idx < SLOTCAP) ws->slotBuf[sl][idx] = ((ull)kk << 24) | (ull)(j0 + e);
        }
      }
    }
  }
  if (gtid < tail) {
    uint32_t j = (nquad << 2) + gtid;
    int sl = bs[bid[j]];
    if (sl >= 0) {
      uint32_t h = atomicAdd(&hcnt, 1u);
      if (h < HCAP) {
        hj[h] = j;
      } else {
        uint32_t kk = tf_bits(sk0, sk1, j);
        uint32_t idx = atomicAdd(&ws->slotCnt[sl], 1u);
        if (idx < SLOTCAP) ws->slotBuf[sl][idx] = ((ull)kk << 24) | (ull)j;
      }
    }
  }
  __syncthreads();
  uint32_t n = hcnt < (uint32_t)HCAP ? hcnt : (uint32_t)HCAP;
  for (uint32_t h = t; h < n; h += blockDim.x) {
    uint32_t kk = tf_bits(sk0, sk1, hj[h]);
    hk[h] = kk;
    atomicAdd(&scnt[bs[kk >> BINSHIFT]], 1u);
  }
  __syncthreads();
  if (t < MAXSLOT) {
    scur[t] = 0u;
    if (scnt[t]) sbase_[t] = atomicAdd(&ws->slotCnt[t], scnt[t]);
  }
  __syncthreads();
  for (uint32_t h = t; h < n; h += blockDim.x) {
    uint32_t kk = hk[h], j = hj[h];
    int sl = bs[kk >> BINSHIFT];
    uint32_t idx = sbase_[sl] + atomicAdd(&scur[sl], 1u);
    if (idx < SLOTCAP) ws->slotBuf[sl][idx] = ((ull)kk << 24) | (ull)j;
  }
}

__device__ __forceinline__ float sl1(float dd) {
  float ad = fabsf(dd);
  return (ad < 1.0f) ? 0.5f * dd * dd : ad - 0.5f;
}

// Counting-sort select for slot=blockIdx.x. doNext: 1 = last-done block runs
// scanloc(m+1); 2 = last-done block computes the final loss (fused k_loss).
__global__ __launch_bounds__(1024) void k_selscan(WS* ws, int m, int doNext,
                                                  const float* __restrict__ reg,
                                                  const float* __restrict__ obj,
                                                  const float4* __restrict__ tgtb,
                                                  const float4* __restrict__ anch,
                                                  float* out) {
  __shared__ ull      srt[SLOTCAP];
  __shared__ uint32_t hh[256];
  __shared__ uint32_t cum[257];
  __shared__ uint32_t cur[256];
  __shared__ uint32_t sb[256];
  __shared__ uint32_t cumS[NBINS + 1];
  __shared__ uint32_t part[1024];
  __shared__ int32_t  bslL[NBINS];
  __shared__ uint32_t nslL;
  __shared__ uint32_t lastF;
  __shared__ double sA[256], sB[256];
  int t = threadIdx.x;
  int slot = blockIdx.x;
  uint32_t nslots = ws->nslots;
  if ((uint32_t)slot < nslots) {
    uint32_t cnt = ws->slotCnt[slot];
    if (cnt > SLOTCAP) cnt = SLOTCAP;
    if (t < 256) hh[t] = 0u;
    __syncthreads();
    for (uint32_t i = t; i < cnt; i += 1024) {
      ull v = ws->slotBuf[slot][i];
      atomicAdd(&hh[(uint32_t)(v >> 35) & 255u], 1u);
    }
    __syncthreads();
    if (t < 256) sb[t] = hh[t];
    __syncthreads();
    for (int off = 1; off < 256; off <<= 1) {
      uint32_t add = (t >= off && t < 256) ? sb[t - off] : 0u;
      __syncthreads();
      if (t < 256) sb[t] += add;
      __syncthreads();
    }
    if (t == 0) cum[0] = 0u;
    if (t < 256) { cum[t + 1] = sb[t]; cur[t] = 0u; }
    __syncthreads();
    for (uint32_t i = t; i < cnt; i += 1024) {
      ull v = ws->slotBuf[slot][i];
      uint32_t bb = (uint32_t)(v >> 35) & 255u;
      uint32_t idx = cum[bb] + atomicAdd(&cur[bb], 1u);
      srt[idx] = v;
    }
    __syncthreads();
    uint32_t k = ws->kcnt[1];
    if (t < (int)k && ws->tslot[t] == (uint32_t)slot) {
      uint32_t tr = ws->tlocal[t];
      uint32_t lo = 0, hi = 256;
      while (hi - lo > 1u) {
        uint32_t mid = (lo + hi) >> 1;
        if (cum[mid] <= tr) lo = mid; else hi = mid;
      }
      uint32_t r2 = tr - cum[lo];
      uint32_t b0 = cum[lo], b1 = cum[lo + 1];
      for (uint32_t x = b0; x < b1; ++x) {
        ull vx = srt[x];
        uint32_t rank = 0;
        for (uint32_t y = b0; y < b1; ++y) rank += (srt[y] < vx) ? 1u : 0u;
        if (rank == r2) { ws->tgt[1][t] = (uint32_t)(vx & 0xFFFFFFull); break; }
      }
    }
  }
  if (doNext) {
    __syncthreads();
    if (t == 0) {
      __threadfence();
      lastF = (atomicAdd(&ws->selDone[m], 1u) == (uint32_t)(gridDim.x - 1)) ? 1u : 0u;
    }
    __syncthreads();
    if (!lastF) return;
    __threadfence();
    if (doNext == 1) {
      scanloc_body(ws, m + 1, cumS, part, bslL, &nslL);
    } else {
      // ---- fused final loss (256 working threads; all hit barriers) ----
      uint32_t npos = ws->n_pos;
      double lr = 0.0, bc = 0.0;
      if (t < 256) {
        int s = t;
        if (s < (int)npos) {
          uint32_t v = ws->tgt[0][s];
          uint32_t pa = ws->T[v];
          uint32_t i = pa >> 6, j = pa & 63u;
          float4 tb = tgtb[j];
          float tcx = (tb.x + tb.z) * 0.5f, tcy = (tb.y + tb.w) * 0.5f;
          float tw = tb.z - tb.x, th = tb.w - tb.y;
          float4 a = anch[i];
          float r0 = (tcx - a.x) / a.z;
          float r1 = (tcy - a.y) / a.w;
          float r2 = logf(tw / a.z);
          float r3 = logf(th / a.w);
          lr = (double)sl1(reg[i * 4 + 0] - r0) + (double)sl1(reg[i * 4 + 1] - r1) +
               (double)sl1(reg[i * 4 + 2] - r2) + (double)sl1(reg[i * 4 + 3] - r3);
          float x = obj[i];
          bc = (double)(fmaxf(x, 0.0f) - x + log1pf(expf(-fabsf(x))));
        } else {
          uint32_t e = ws->tgt[1][s - (int)npos];
          uint32_t P = ws->P;
          uint32_t lo = 0, hi = P;
          while (lo < hi) {
            uint32_t mid = (lo + hi) >> 1;
            if (ws->T[mid] - mid > e) hi = mid; else lo = mid + 1;
          }
          uint32_t f = e + lo;
          uint32_t i = f >> 6;
          float x = obj[i];
          bc = (double)(fmaxf(x, 0.0f) + log1pf(expf(-fabsf(x))));
        }
        sA[t] = lr; sB[t] = bc;
      }
      __syncthreads();
      for (int off = 128; off > 0; off >>= 1) {
        if (t < off) { sA[t] += sA[t + off]; sB[t] += sB[t + off]; }
        __syncthreads();
      }
      if (t == 0)
        out[0] = (float)(sA[0] * (10.0 / 2500.0) + sB[0] * (1.0 / 256.0));
    }
  }
}

extern "C" void kernel_launch(void* const* d_in, const int* in_sizes, int n_in,
                              void* d_out, int out_size, void* d_ws,
                              size_t ws_size, hipStream_t stream) {
  const float*  reg  = (const float*)d_in[0];
  const float*  obj  = (const float*)d_in[1];
  const float4* pred = (const float4*)d_in[2];
  const float4* tgtb = (const float4*)d_in[3];
  const float4* anch = (const float4*)d_in[4];
  float* out = (float*)d_out;
  WS* ws = (WS*)d_ws;
  (void)in_sizes; (void)n_in; (void)out_size; (void)ws_size;

  hipMemsetAsync(d_ws, 0, ZBYTES, stream);   // ctrl counters + lookback
  k_iou<<<IBLK, 1024, 0, stream>>>(pred, tgtb, ws);
  k_scan_emit<<<CBLK, 256, 0, stream>>>(ws);
  k_histA<<<HBLK, 1024, 0, stream>>>(ws);
  k_redscan<<<HRED + 1, 1024, 0, stream>>>(ws);  // reduce + scanloc0 + pos
  for (int m = 0; m < 3; ++m) {
    k_gather<<<CBLK, 1024, 0, stream>>>(ws, m);
    k_selscan<<<MAXSLOT, 1024, 0, stream>>>(ws, m, (m < 2) ? 1 : 2,
                                            reg, obj, tgtb, anch, out);
  }
}

// Round 15
// 199.433 us; speedup vs baseline: 2.3127x; 1.1353x over previous
//
#include <hip/hip_runtime.h>
#include <stdint.h>

// ---------------------------------------------------------------------------
// RPN loss: IoU>0.7 matching + argmax fix + exact JAX threefry sampling
// (partitionable PRNG path) + smooth-L1 + BCE, all on device.
// R1-R7: algorithmic fixes (2785 -> 314us). R8-R14: launch collapse, fence
// repair, occupancy repair, 3-in-1 hist (226us).
// R15: round m=0's target ranks are SEQUENTIAL 0..n_neg-1 => it's a global
// top-K by (key,pos). histA filters key < 2^20 (exp. 2048 of 8.39M) into
// topBuf instead of histogramming round 0; k_redscan block 33 counting-sorts
// topBuf -> tgt[1] and then runs scanloc(1). Deletes gather(0)+selscan(0),
// 1/3 of hist atomics/stores/reduce. Launches 11 -> 9.
// ---------------------------------------------------------------------------

#define N_PRED   131072
#define NBOXK    64
#define NM_TOT   8388608u          // N_PRED * NBOXK
#define TCAP     65536
#define NBINS    8192
#define BINSHIFT 19                // key >> 19 -> 13-bit bin
#define SLOTCAP  3072
#define MAXSLOT  192
#define HCAP     2048              // per-block LDS hit buffer (gather)
#define CBLK     512               // scan blocks
#define IBLK     128               // iou blocks (1024 thr each)
#define POSCAP   32                // per-bin candidate cap in pos chain
#define HBLK     512               // hist worker blocks
#define HRED     32                // reducer blocks (2 rounds x 4096 cols)
#define FILT     (1u << 20)        // top-K filter threshold (exp. count 2048)
#define TOPCAP   6144              // filter capacity (mean + ~91 sigma)

typedef unsigned long long ull;

struct WS {
  // ---- zeroed by hipMemsetAsync at the head of every launch ----
  uint32_t iouDone, redDone, selDone[3], topCnt, zpad[2];     // 32B
  ull      lookback[CBLK];                                    // 4KB
  // ---- end zero region (ZBYTES) ----
  uint32_t P, M, n_pos, n_neg;
  uint32_t R[2], S[2], kcnt[2];
  uint32_t sub[2][3][2];            // per-round subkeys
  uint32_t nslots;
  uint32_t hist3[3][NBINS];         // reduced hists ([1],[2] used)
  ull      colBestBlk[IBLK][NBOXK]; // per-block iou argmax partials
  ull      maskWords[N_PRED];
  uint32_t T[TCAP];
  uint32_t tgt[2][256];
  int32_t  binslot[NBINS];
  int32_t  tslot[256];
  uint32_t tlocal[256];
  uint32_t slotCnt[MAXSLOT];
  ull      topBuf[TOPCAP];          // filtered (key<<24|pos) for round m=0
  ull      slotBuf[MAXSLOT][SLOTCAP];
  uint32_t hist3Blk[3][HBLK][4096]; // per-block u16-pair hist slices
  uint16_t binid3[3][NM_TOT];       // bin-id caches ([1],[2] used)
};
#define ZBYTES (32 + CBLK*8)

// rotate-left via v_alignbit_b32 (single VALU op)
__device__ __forceinline__ uint32_t rotl(uint32_t x, uint32_t r) {
  return __builtin_amdgcn_alignbit(x, x, 32u - r);
}

// Threefry-2x32-20, matches JAX reference implementation exactly.
__device__ __forceinline__ void tf2(uint32_t k0, uint32_t k1,
                                    uint32_t& x0, uint32_t& x1) {
  uint32_t k2 = k0 ^ k1 ^ 0x1BD11BDAu;
  x0 += k0; x1 += k1;
#define QR(r) { x0 += x1; x1 = rotl(x1, r); x1 ^= x0; }
  QR(13) QR(15) QR(26) QR(6)  x0 += k1; x1 += k2 + 1u;
  QR(17) QR(29) QR(16) QR(24) x0 += k2; x1 += k0 + 2u;
  QR(13) QR(15) QR(26) QR(6)  x0 += k0; x1 += k1 + 3u;
  QR(17) QR(29) QR(16) QR(24) x0 += k1; x1 += k2 + 4u;
  QR(13) QR(15) QR(26) QR(6)  x0 += k2; x1 += k0 + 5u;
#undef QR
}

__device__ __forceinline__ uint32_t tf_bits(uint32_t k0, uint32_t k1, uint32_t p) {
  uint32_t a = 0u, b = p;
  tf2(k0, k1, a, b);
  return a ^ b;
}

__device__ __forceinline__ ull umax64(ull a, ull b) { return a > b ? a : b; }

// IoU mask + per-column argmax. Lane l owns column l; 8-row register
// prefetch; 1024-thread blocks; last-done block reduces + "need" fixup.
__global__ __launch_bounds__(1024) void k_iou(const float4* __restrict__ pred,
                                              const float4* __restrict__ tgtb,
                                              WS* ws) {
  __shared__ float4 sp[1024];
  __shared__ ull cb[NBOXK];
  __shared__ ull red2[16][NBOXK];
  __shared__ uint32_t lastF;
  int t = threadIdx.x;
  int lane = t & 63;
  int w = t >> 6;
  int rowBase = blockIdx.x * 1024;
  sp[t] = pred[rowBase + t];
  if (t < NBOXK) cb[t] = 0ull;
  float4 tb = tgtb[lane];
  float ta = __fmul_rn(__fsub_rn(tb.z, tb.x), __fsub_rn(tb.w, tb.y));
  __syncthreads();
  ull myWord = 0ull;
  float bestI = -1.0f;
  uint32_t bestRow = 0u;
  int wbase = w * 64;
  for (int r0 = 0; r0 < 64; r0 += 8) {
    float4 pr[8];
#pragma unroll
    for (int e = 0; e < 8; ++e) pr[e] = sp[wbase + r0 + e];
#pragma unroll
    for (int e = 0; e < 8; ++e) {
      float4 p = pr[e];
      float pa = __fmul_rn(__fsub_rn(p.z, p.x), __fsub_rn(p.w, p.y));
      float ltx = fmaxf(p.x, tb.x), lty = fmaxf(p.y, tb.y);
      float rbx = fminf(p.z, tb.z), rby = fminf(p.w, tb.w);
      float wx = fmaxf(__fsub_rn(rbx, ltx), 0.0f);
      float wy = fmaxf(__fsub_rn(rby, lty), 0.0f);
      float inter = __fmul_rn(wx, wy);
      float uni = __fsub_rn(__fadd_rn(pa, ta), inter);
      float iou = __fdiv_rn(inter, uni);
      ull bal = __ballot(iou > 0.7f);
      if (lane == (r0 + e)) myWord = bal;
      if (iou > bestI) { bestI = iou; bestRow = (uint32_t)(rowBase + wbase + r0 + e); }
    }
  }
  ws->maskWords[rowBase + wbase + lane] = myWord;
  ull pk = ((ull)__float_as_uint(bestI) << 32) | (ull)(~bestRow);
  atomicMax(&cb[lane], pk);
  __syncthreads();
  if (t < NBOXK) ws->colBestBlk[blockIdx.x][t] = cb[t];
  if (t == 0) {
    __threadfence();                  // one wbl2 per block
    lastF = (atomicAdd(&ws->iouDone, 1u) == (uint32_t)(gridDim.x - 1)) ? 1u : 0u;
  }
  __syncthreads();
  if (lastF) {
    __threadfence();
    int c = t & 63, q = t >> 6;
    ull best = 0ull;
    for (int b = q; b < IBLK; b += 16) best = umax64(best, ws->colBestBlk[b][c]);
    red2[q][c] = best;
    __syncthreads();
    if (t < NBOXK) {
      ull m_ = red2[0][t];
#pragma unroll
      for (int q2 = 1; q2 < 16; ++q2) m_ = umax64(m_, red2[q2][t]);
      float bi = __uint_as_float((uint32_t)(m_ >> 32));
      if (!(bi > 0.7f)) {
        uint32_t row = ~(uint32_t)(m_ & 0xFFFFFFFFu);
        atomicOr(&ws->maskWords[row], 1ull << t);
      }
    }
  }
}

// Fused count + global scan (windowed wave-parallel lookback) + ordered emit;
// block 511 does the scalar/PRNG setup.
__global__ __launch_bounds__(256) void k_scan_emit(WS* ws) {
  __shared__ uint32_t sm[256];
  __shared__ uint32_t exclS;
  int t = threadIdx.x, b = blockIdx.x;
  int row = b * 256 + t;
  ull w = ws->maskWords[row];
  uint32_t c = (uint32_t)__popcll(w);
  sm[t] = c;
  __syncthreads();
  for (int off = 1; off < 256; off <<= 1) {
    uint32_t add = (t >= off) ? sm[t - off] : 0u;
    __syncthreads();
    sm[t] += add;
    __syncthreads();
  }
  uint32_t mySum = sm[255];
  if (t == 0) {
    if (b == 0) {
      atomicExch(&ws->lookback[0], (2ull << 32) | (ull)mySum);
      exclS = 0u;
    } else {
      atomicExch(&ws->lookback[b], (1ull << 32) | (ull)mySum);
    }
    __threadfence();
  }
  if (b > 0 && t < 64) {
    int i = b - 1;
    uint32_t run = 0u;
    while (true) {
      int idx = i - t;
      ull x = (idx >= 0) ? atomicAdd(&ws->lookback[idx], 0ull) : (2ull << 32);
      uint32_t st = (uint32_t)(x >> 32);
      ull b2 = __ballot(st == 2u);
      ull b0 = __ballot(st == 0u);
      int f2 = (b2 == 0ull) ? 64 : (__ffsll((long long)b2) - 1);
      int f0 = (b0 == 0ull) ? 64 : (__ffsll((long long)b0) - 1);
      if (f0 < f2) continue;
      uint32_t v = (t <= f2) ? (uint32_t)x : 0u;
#pragma unroll
      for (int o = 32; o > 0; o >>= 1) v += __shfl_xor(v, o, 64);
      run += v;
      if (f2 < 64) break;
      i -= 64;
    }
    if (t == 0) {
      atomicExch(&ws->lookback[b], (2ull << 32) | (ull)(run + mySum));
      exclS = run;
    }
  }
  __syncthreads();
  uint32_t off0 = exclS + sm[t] - c;
  while (w) {
    int bit = __ffsll((long long)w) - 1;
    w &= (w - 1);
    if (off0 < TCAP) ws->T[off0] = ((uint32_t)row << 6) | (uint32_t)bit;
    off0++;
  }
  if (b == CBLK - 1) {
    ws->tgt[0][t] = (uint32_t)t;
    ws->tgt[1][t] = (uint32_t)t;
    if (t == 0) {
      uint32_t total = exclS + mySum;
      uint32_t P = total < (uint32_t)TCAP ? total : (uint32_t)TCAP;
      uint32_t M = NM_TOT - P;
      uint32_t npos = P < 128u ? P : 128u;
      ws->P = P; ws->M = M;
      ws->n_pos = npos; ws->n_neg = 256u - npos;
      ws->S[0] = P; ws->S[1] = M;
      ws->kcnt[0] = npos; ws->kcnt[1] = 256u - npos;
      const double LOGU = 22.18070977791825;  // log(2^32 - 1)
      for (int d = 0; d < 2; ++d) {
        uint32_t Sd = ws->S[d];
        int R = 0;
        if (Sd > 1u) {
          R = (int)ceil(3.0 * log((double)Sd) / LOGU);
          if (R < 1) R = 1;
          if (R > 3) R = 3;
        }
        ws->R[d] = (uint32_t)R;
        uint32_t ck0, ck1;
        { uint32_t a = 0u, bb = (uint32_t)d; tf2(0u, 42u, a, bb); ck0 = a; ck1 = bb; }
        for (int rr = 0; rr < 3; ++rr) {
          uint32_t s0 = 0u, s1 = 1u; tf2(ck0, ck1, s0, s1);
          ws->sub[d][rr][0] = s0; ws->sub[d][rr][1] = s1;
          uint32_t n0 = 0u, n1 = 0u; tf2(ck0, ck1, n0, n1);
          ck0 = n0; ck1 = n1;
        }
      }
    }
  }
}

// Rounds m=1,2: hist + binid caches (8 indep threefry chains/quad, 8 LDS
// atomics, 2 u64 stores). Round m=0: top-K filter only (4 hashes, compare,
// rare global append). 32KB LDS -> 2 blocks/CU.
__global__ __launch_bounds__(1024) void k_histA(WS* ws) {
  __shared__ uint32_t lh[2][4096];   // 32KB
  const uint32_t M = ws->M;
  uint32_t nquad = M >> 2, tail = M & 3u;
  uint32_t gtid = blockIdx.x * 1024u + threadIdx.x;
  const uint32_t stride = (uint32_t)HBLK * 1024u;
  uint32_t skA0 = ws->sub[1][2][0], skA1 = ws->sub[1][2][1];  // m=0 (filter)
  uint32_t skB0 = ws->sub[1][1][0], skB1 = ws->sub[1][1][1];  // m=1
  uint32_t skC0 = ws->sub[1][0][0], skC1 = ws->sub[1][0][1];  // m=2
  for (int i = threadIdx.x; i < 2 * 4096; i += 1024) (&lh[0][0])[i] = 0u;
  __syncthreads();
  for (uint32_t q = gtid; q < nquad; q += stride) {
    uint32_t j = q << 2;
    // m=0 filter: append (key<<24|pos) for key < FILT (expected ~0.024%/elem)
#pragma unroll
    for (int e = 0; e < 4; ++e) {
      uint32_t kk = tf_bits(skA0, skA1, j + (uint32_t)e);
      if (kk < FILT) {
        uint32_t idx = atomicAdd(&ws->topCnt, 1u);
        if (idx < TOPCAP)
          ws->topBuf[idx] = ((ull)kk << 24) | (ull)(j + (uint32_t)e);
      }
    }
#define HQUAD(li, mm, K0, K1)                                                 \
    {                                                                         \
      uint32_t k0 = tf_bits(K0, K1, j);                                       \
      uint32_t k1 = tf_bits(K0, K1, j + 1);                                   \
      uint32_t k2 = tf_bits(K0, K1, j + 2);                                   \
      uint32_t k3 = tf_bits(K0, K1, j + 3);                                   \
      uint32_t b0 = k0 >> BINSHIFT, b1 = k1 >> BINSHIFT;                      \
      uint32_t b2 = k2 >> BINSHIFT, b3 = k3 >> BINSHIFT;                      \
      *(ull*)(ws->binid3[mm] + j) =                                           \
          (ull)b0 | ((ull)b1 << 16) | ((ull)b2 << 32) | ((ull)b3 << 48);      \
      atomicAdd(&lh[li][b0 >> 1], (b0 & 1) ? 0x10000u : 1u);                  \
      atomicAdd(&lh[li][b1 >> 1], (b1 & 1) ? 0x10000u : 1u);                  \
      atomicAdd(&lh[li][b2 >> 1], (b2 & 1) ? 0x10000u : 1u);                  \
      atomicAdd(&lh[li][b3 >> 1], (b3 & 1) ? 0x10000u : 1u);                  \
    }
    HQUAD(0, 1, skB0, skB1)
    HQUAD(1, 2, skC0, skC1)
#undef HQUAD
  }
  if (gtid < tail) {
    uint32_t j = (nquad << 2) + gtid;
    {
      uint32_t kk = tf_bits(skA0, skA1, j);
      if (kk < FILT) {
        uint32_t idx = atomicAdd(&ws->topCnt, 1u);
        if (idx < TOPCAP) ws->topBuf[idx] = ((ull)kk << 24) | (ull)j;
      }
    }
#define HTAIL(li, mm, K0, K1)                                                 \
    {                                                                         \
      uint32_t k0 = tf_bits(K0, K1, j);                                       \
      uint32_t b0 = k0 >> BINSHIFT;                                           \
      ws->binid3[mm][j] = (uint16_t)b0;                                       \
      atomicAdd(&lh[li][b0 >> 1], (b0 & 1) ? 0x10000u : 1u);                  \
    }
    HTAIL(0, 1, skB0, skB1)
    HTAIL(1, 2, skC0, skC1)
#undef HTAIL
  }
  __syncthreads();
  for (int i = threadIdx.x; i < 4096; i += 1024) {
    ws->hist3Blk[1][blockIdx.x][i] = lh[0][i];
    ws->hist3Blk[2][blockIdx.x][i] = lh[1][i];
  }
}

// scanloc body (1024 threads): LDS scan of hist3[m], per-target binary
// search, LDS bin dedup; writes binslot map + zeroes slotCnt/nslots.
__device__ void scanloc_body(WS* ws, int m, uint32_t* cumS, uint32_t* part,
                             int32_t* bslL, uint32_t* nslL) {
  int t = threadIdx.x;
  const int E = NBINS / 1024;
  uint32_t lv[E];
  uint32_t s = 0;
  uint32_t base = (uint32_t)t * E;
#pragma unroll
  for (int e = 0; e < E; ++e) { lv[e] = ws->hist3[m][base + e]; s += lv[e]; }
  part[t] = s;
  for (int i = t; i < NBINS; i += 1024) bslL[i] = -1;
  if (t == 0) *nslL = 0u;
  __syncthreads();
  for (int off = 1; off < 1024; off <<= 1) {
    uint32_t add = (t >= off) ? part[t - off] : 0u;
    __syncthreads();
    part[t] += add;
    __syncthreads();
  }
  uint32_t run = part[t] - s;
#pragma unroll
  for (int e = 0; e < E; ++e) { cumS[base + e] = run; run += lv[e]; }
  if (t == 1023) cumS[NBINS] = run;
  __syncthreads();
  uint32_t k = ws->kcnt[1];
  uint32_t lo = 0; int old = 0;
  if (t < (int)k) {
    uint32_t tr = ws->tgt[1][t];
    uint32_t hi = NBINS;
    while (hi - lo > 1u) {
      uint32_t mid = (lo + hi) >> 1;
      if (cumS[mid] <= tr) lo = mid; else hi = mid;
    }
    ws->tlocal[t] = tr - cumS[lo];
    old = atomicCAS(&bslL[lo], -1, (int)(0x10000u + (uint32_t)t));
  }
  __syncthreads();
  if (t < (int)k && old == -1) {
    uint32_t sl = atomicAdd(nslL, 1u);
    bslL[lo] = (int)sl;
  }
  __syncthreads();
  if (t < (int)k) ws->tslot[t] = (uint32_t)bslL[lo];
  for (int i = t; i < NBINS; i += 1024) ws->binslot[i] = bslL[i];
  if (t < MAXSLOT) ws->slotCnt[t] = 0u;
  if (t == 0) ws->nslots = *nslL;
}

union RedU {
  struct { uint32_t plo[4][256], phi[4][256]; } red;                  // 8KB
  struct { ull srt[TOPCAP]; uint32_t hh[256], cum[257], cur[256],
           sb[256]; } top;                                            // 52KB
  struct { uint32_t cumS[NBINS + 1]; uint32_t part[1024];
           int32_t bsl[NBINS]; uint32_t nsl; } scan;                  // 68KB
  struct { uint32_t h8[NBINS]; uint32_t part[1024]; int32_t bsl[NBINS];
           ull sbuf[128][POSCAP]; uint32_t scntL[128];
           uint32_t tg[256], tlo[256], tsl[256]; uint32_t nsl; } pos; // 104KB
};

// blocks 0..31: reduce hist3Blk[1],[2] -> hist3. Block 32: pos chain.
// Block 33: top-K counting-sort -> tgt[1], then (after reduce) scanloc(1).
__global__ __launch_bounds__(1024) void k_redscan(WS* ws) {
  __shared__ RedU su;
  int b = blockIdx.x, t = threadIdx.x;

  if (b == HRED) {
    // ---------------- pos chain ----------------
    int R = (int)ws->R[0];
    uint32_t P = ws->P;
    uint32_t k = ws->kcnt[0];
    if (R < 1) return;
    if (t < 256) su.pos.tg[t] = (uint32_t)t;
    __syncthreads();
    for (int r = R; r >= 1; --r) {
      uint32_t sk0 = ws->sub[0][r - 1][0], sk1 = ws->sub[0][r - 1][1];
      for (int i = t; i < NBINS; i += 1024) su.pos.h8[i] = 0u;
      __syncthreads();
      for (uint32_t j = t; j < P; j += 1024)
        atomicAdd(&su.pos.h8[tf_bits(sk0, sk1, j) >> BINSHIFT], 1u);
      __syncthreads();
      uint32_t lv[NBINS / 1024];
      uint32_t s = 0;
      uint32_t base = (uint32_t)t * (NBINS / 1024);
#pragma unroll
      for (int e = 0; e < NBINS / 1024; ++e) { lv[e] = su.pos.h8[base + e]; s += lv[e]; }
      su.pos.part[t] = s;
      __syncthreads();
      for (int off = 1; off < 1024; off <<= 1) {
        uint32_t add = (t >= off) ? su.pos.part[t - off] : 0u;
        __syncthreads();
        su.pos.part[t] += add;
        __syncthreads();
      }
      uint32_t run = su.pos.part[t] - s;
#pragma unroll
      for (int e = 0; e < NBINS / 1024; ++e) { su.pos.h8[base + e] = run; run += lv[e]; }
      for (int i = t; i < NBINS; i += 1024) su.pos.bsl[i] = -1;
      if (t == 0) su.pos.nsl = 0u;
      if (t < 128) su.pos.scntL[t] = 0u;
      __syncthreads();
      uint32_t lo = 0; int old = 0;
      if (t < (int)k) {
        uint32_t tr = su.pos.tg[t];
        uint32_t hi = NBINS;
        while (hi - lo > 1u) {
          uint32_t mid = (lo + hi) >> 1;
          if (su.pos.h8[mid] <= tr) lo = mid; else hi = mid;
        }
        su.pos.tlo[t] = tr - su.pos.h8[lo];
        old = atomicCAS(&su.pos.bsl[lo], -1, (int)(0x10000u + (uint32_t)t));
      }
      __syncthreads();
      if (t < (int)k && old == -1) {
        uint32_t sl = atomicAdd(&su.pos.nsl, 1u);
        su.pos.bsl[lo] = (int)sl;
      }
      __syncthreads();
      if (t < (int)k) su.pos.tsl[t] = (uint32_t)su.pos.bsl[lo];
      __syncthreads();
      for (uint32_t j = t; j < P; j += 1024) {
        uint32_t kk = tf_bits(sk0, sk1, j);
        int sl = su.pos.bsl[kk >> BINSHIFT];
        if (sl >= 0) {
          uint32_t idx = atomicAdd(&su.pos.scntL[sl], 1u);
          if (idx < POSCAP) su.pos.sbuf[sl][idx] = ((ull)kk << 24) | (ull)j;
        }
      }
      __syncthreads();
      if (t < (int)k) {
        uint32_t sl = su.pos.tsl[t], r2 = su.pos.tlo[t];
        uint32_t cn = su.pos.scntL[sl] < POSCAP ? su.pos.scntL[sl] : POSCAP;
        for (uint32_t x = 0; x < cn; ++x) {
          ull vx = su.pos.sbuf[sl][x];
          uint32_t rank = 0;
          for (uint32_t y = 0; y < cn; ++y) rank += (su.pos.sbuf[sl][y] < vx) ? 1u : 0u;
          if (rank == r2) { su.pos.tg[t] = (uint32_t)(vx & 0xFFFFFFull); break; }
        }
      }
      __syncthreads();
    }
    if (t < (int)k) ws->tgt[0][t] = su.pos.tg[t];
    return;
  }

  if (b == HRED + 1) {
    // -------- top-K: counting-sort topBuf by kk>>12, emit tgt[1] --------
    uint32_t cnt = ws->topCnt; if (cnt > TOPCAP) cnt = TOPCAP;
    uint32_t kcnt = ws->kcnt[1];
    if (t < 256) su.top.hh[t] = 0u;
    __syncthreads();
    for (uint32_t i = t; i < cnt; i += 1024)
      atomicAdd(&su.top.hh[(uint32_t)(ws->topBuf[i] >> 36) & 255u], 1u);
    __syncthreads();
    if (t < 256) su.top.sb[t] = su.top.hh[t];
    __syncthreads();
    for (int off = 1; off < 256; off <<= 1) {
      uint32_t add = (t >= off && t < 256) ? su.top.sb[t - off] : 0u;
      __syncthreads();
      if (t < 256) su.top.sb[t] += add;
      __syncthreads();
    }
    if (t == 0) su.top.cum[0] = 0u;
    if (t < 256) { su.top.cum[t + 1] = su.top.sb[t]; su.top.cur[t] = 0u; }
    __syncthreads();
    for (uint32_t i = t; i < cnt; i += 1024) {
      ull v = ws->topBuf[i];
      uint32_t b8 = (uint32_t)(v >> 36) & 255u;
      uint32_t idx = su.top.cum[b8] + atomicAdd(&su.top.cur[b8], 1u);
      if (idx < TOPCAP) su.top.srt[idx] = v;
    }
    __syncthreads();
    if (t < (int)kcnt) {
      uint32_t tr = (uint32_t)t;           // sequential target ranks
      uint32_t lo = 0, hi = 256;
      while (hi - lo > 1u) {
        uint32_t mid = (lo + hi) >> 1;
        if (su.top.cum[mid] <= tr) lo = mid; else hi = mid;
      }
      uint32_t r2 = tr - su.top.cum[lo];
      uint32_t b0 = su.top.cum[lo], b1 = su.top.cum[lo + 1];
      for (uint32_t x = b0; x < b1; ++x) {
        ull vx = su.top.srt[x];
        uint32_t rank = 0;
        for (uint32_t y = b0; y < b1; ++y) rank += (su.top.srt[y] < vx) ? 1u : 0u;
        if (rank == r2) { ws->tgt[1][t] = (uint32_t)(vx & 0xFFFFFFull); break; }
      }
    }
    __syncthreads();
    // -------- wait for hist reduce, then scanloc round m=1 --------
    if (t == 0) {
      while (atomicAdd(&ws->redDone, 0u) < (uint32_t)HRED)
        __builtin_amdgcn_s_sleep(2);
    }
    __syncthreads();
    __threadfence();
    scanloc_body(ws, 1, su.scan.cumS, su.scan.part, su.scan.bsl, &su.scan.nsl);
    return;
  }

  // ---------------- reducers (blocks 0..31) ----------------
  {
    uint32_t c = (uint32_t)b * 256u + ((uint32_t)t & 255u);   // 0..8191
    uint32_t m_ = 1u + (c >> 12), i_ = c & 4095u;
    uint32_t p = (uint32_t)t >> 8;
    uint32_t lo = 0u, hi = 0u;
    for (uint32_t blk = p; blk < (uint32_t)HBLK; blk += 4u) {
      uint32_t v = ws->hist3Blk[m_][blk][i_];
      lo += v & 0xFFFFu; hi += v >> 16;
    }
    su.red.plo[p][t & 255] = lo;
    su.red.phi[p][t & 255] = hi;
  }
  __syncthreads();
  if (t < 256) {
    uint32_t l2 = su.red.plo[0][t] + su.red.plo[1][t] + su.red.plo[2][t] + su.red.plo[3][t];
    uint32_t h2 = su.red.phi[0][t] + su.red.phi[1][t] + su.red.phi[2][t] + su.red.phi[3][t];
    uint32_t cc = (uint32_t)b * 256u + (uint32_t)t;
    uint32_t mm = 1u + (cc >> 12), ii = cc & 4095u;
    ws->hist3[mm][2 * ii]     = l2;
    ws->hist3[mm][2 * ii + 1] = h2;
  }
  __syncthreads();
  if (t == 0) {
    __threadfence();
    atomicAdd(&ws->redDone, 1u);
  }
}

// binid scanned as u64 quads -> LDS compaction -> threefry for hits only ->
// range-reserved slotBuf writes.
__global__ __launch_bounds__(1024) void k_gather(WS* ws, int m) {
  __shared__ int bs[NBINS];
  __shared__ uint32_t hk[HCAP];
  __shared__ uint32_t hj[HCAP];
  __shared__ uint32_t scnt[MAXSLOT];
  __shared__ uint32_t sbase_[MAXSLOT];
  __shared__ uint32_t scur[MAXSLOT];
  __shared__ uint32_t hcnt;
  int t = threadIdx.x;
  for (int i = t; i < NBINS; i += blockDim.x) bs[i] = ws->binslot[i];
  if (t < MAXSLOT) scnt[t] = 0u;
  if (t == 0) hcnt = 0u;
  __syncthreads();
  uint32_t S = ws->M;
  uint32_t sk0 = ws->sub[1][2 - m][0], sk1 = ws->sub[1][2 - m][1];
  const uint16_t* bid = ws->binid3[m];
  const ull* bid4 = (const ull*)bid;
  uint32_t nquad = S >> 2, tail = S & 3u;
  uint32_t gtid = blockIdx.x * blockDim.x + t;
  uint32_t stride = gridDim.x * blockDim.x;
  for (uint32_t q = gtid; q < nquad; q += stride) {
    ull v4 = bid4[q];
    uint32_t j0 = q << 2;
#pragma unroll
    for (int e = 0; e < 4; ++e) {
      uint32_t bb = (uint32_t)(v4 >> (16 * e)) & 0xFFFFu;
      int sl = bs[bb];
      if (sl >= 0) {
        uint32_t h = atomicAdd(&hcnt, 1u);
        if (h < HCAP) {
          hj[h] = j0 + (uint32_t)e;
        } else {
          uint32_t kk = tf_bits(sk0, sk1, j0 + (uint32_t)e);
          uint32_t idx = atomicAdd(&ws->slotCnt[sl], 1u);
          if (idx < SLOTCAP) ws->slotBuf[sl][idx] = ((ull)kk << 24) | (ull)(j0 + e);
        }
      }
    }
  }
  if (gtid < tail) {
    uint32_t j = (nquad << 2) + gtid;
    int sl = bs[bid[j]];
    if (sl >= 0) {
      uint32_t h = atomicAdd(&hcnt, 1u);
      if (h < HCAP) {
        hj[h] = j;
      } else {
        uint32_t kk = tf_bits(sk0, sk1, j);
        uint32_t idx = atomicAdd(&ws->slotCnt[sl], 1u);
        if (idx < SLOTCAP) ws->slotBuf[sl][idx] = ((ull)kk << 24) | (ull)j;
      }
    }
  }
  __syncthreads();
  uint32_t n = hcnt < (uint32_t)HCAP ? hcnt : (uint32_t)HCAP;
  for (uint32_t h = t; h < n; h += blockDim.x) {
    uint32_t kk = tf_bits(sk0, sk1, hj[h]);
    hk[h] = kk;
    atomicAdd(&scnt[bs[kk >> BINSHIFT]], 1u);
  }
  __syncthreads();
  if (t < MAXSLOT) {
    scur[t] = 0u;
    if (scnt[t]) sbase_[t] = atomicAdd(&ws->slotCnt[t], scnt[t]);
  }
  __syncthreads();
  for (uint32_t h = t; h < n; h += blockDim.x) {
    uint32_t kk = hk[h], j = hj[h];
    int sl = bs[kk >> BINSHIFT];
    uint32_t idx = sbase_[sl] + atomicAdd(&scur[sl], 1u);
    if (idx < SLOTCAP) ws->slotBuf[sl][idx] = ((ull)kk << 24) | (ull)j;
  }
}

__device__ __forceinline__ float sl1(float dd) {
  float ad = fabsf(dd);
  return (ad < 1.0f) ? 0.5f * dd * dd : ad - 0.5f;
}

// Counting-sort select for slot=blockIdx.x. doNext: 1 = last-done block runs
// scanloc(m+1); 2 = last-done block computes the final loss (fused k_loss).
__global__ __launch_bounds__(1024) void k_selscan(WS* ws, int m, int doNext,
                                                  const float* __restrict__ reg,
                                                  const float* __restrict__ obj,
                                                  const float4* __restrict__ tgtb,
                                                  const float4* __restrict__ anch,
                                                  float* out) {
  __shared__ ull      srt[SLOTCAP];
  __shared__ uint32_t hh[256];
  __shared__ uint32_t cum[257];
  __shared__ uint32_t cur[256];
  __shared__ uint32_t sb[256];
  __shared__ uint32_t cumS[NBINS + 1];
  __shared__ uint32_t part[1024];
  __shared__ int32_t  bslL[NBINS];
  __shared__ uint32_t nslL;
  __shared__ uint32_t lastF;
  __shared__ double sA[256], sB[256];
  int t = threadIdx.x;
  int slot = blockIdx.x;
  uint32_t nslots = ws->nslots;
  if ((uint32_t)slot < nslots) {
    uint32_t cnt = ws->slotCnt[slot];
    if (cnt > SLOTCAP) cnt = SLOTCAP;
    if (t < 256) hh[t] = 0u;
    __syncthreads();
    for (uint32_t i = t; i < cnt; i += 1024) {
      ull v = ws->slotBuf[slot][i];
      atomicAdd(&hh[(uint32_t)(v >> 35) & 255u], 1u);
    }
    __syncthreads();
    if (t < 256) sb[t] = hh[t];
    __syncthreads();
    for (int off = 1; off < 256; off <<= 1) {
      uint32_t add = (t >= off && t < 256) ? sb[t - off] : 0u;
      __syncthreads();
      if (t < 256) sb[t] += add;
      __syncthreads();
    }
    if (t == 0) cum[0] = 0u;
    if (t < 256) { cum[t + 1] = sb[t]; cur[t] = 0u; }
    __syncthreads();
    for (uint32_t i = t; i < cnt; i += 1024) {
      ull v = ws->slotBuf[slot][i];
      uint32_t bb = (uint32_t)(v >> 35) & 255u;
      uint32_t idx = cum[bb] + atomicAdd(&cur[bb], 1u);
      srt[idx] = v;
    }
    __syncthreads();
    uint32_t k = ws->kcnt[1];
    if (t < (int)k && ws->tslot[t] == (uint32_t)slot) {
      uint32_t tr = ws->tlocal[t];
      uint32_t lo = 0, hi = 256;
      while (hi - lo > 1u) {
        uint32_t mid = (lo + hi) >> 1;
        if (cum[mid] <= tr) lo = mid; else hi = mid;
      }
      uint32_t r2 = tr - cum[lo];
      uint32_t b0 = cum[lo], b1 = cum[lo + 1];
      for (uint32_t x = b0; x < b1; ++x) {
        ull vx = srt[x];
        uint32_t rank = 0;
        for (uint32_t y = b0; y < b1; ++y) rank += (srt[y] < vx) ? 1u : 0u;
        if (rank == r2) { ws->tgt[1][t] = (uint32_t)(vx & 0xFFFFFFull); break; }
      }
    }
  }
  if (doNext) {
    __syncthreads();
    if (t == 0) {
      __threadfence();
      lastF = (atomicAdd(&ws->selDone[m], 1u) == (uint32_t)(gridDim.x - 1)) ? 1u : 0u;
    }
    __syncthreads();
    if (!lastF) return;
    __threadfence();
    if (doNext == 1) {
      scanloc_body(ws, m + 1, cumS, part, bslL, &nslL);
    } else {
      // ---- fused final loss (256 working threads; all hit barriers) ----
      uint32_t npos = ws->n_pos;
      double lr = 0.0, bc = 0.0;
      if (t < 256) {
        int s = t;
        if (s < (int)npos) {
          uint32_t v = ws->tgt[0][s];
          uint32_t pa = ws->T[v];
          uint32_t i = pa >> 6, j = pa & 63u;
          float4 tb = tgtb[j];
          float tcx = (tb.x + tb.z) * 0.5f, tcy = (tb.y + tb.w) * 0.5f;
          float tw = tb.z - tb.x, th = tb.w - tb.y;
          float4 a = anch[i];
          float r0 = (tcx - a.x) / a.z;
          float r1 = (tcy - a.y) / a.w;
          float r2 = logf(tw / a.z);
          float r3 = logf(th / a.w);
          lr = (double)sl1(reg[i * 4 + 0] - r0) + (double)sl1(reg[i * 4 + 1] - r1) +
               (double)sl1(reg[i * 4 + 2] - r2) + (double)sl1(reg[i * 4 + 3] - r3);
          float x = obj[i];
          bc = (double)(fmaxf(x, 0.0f) - x + log1pf(expf(-fabsf(x))));
        } else {
          uint32_t e = ws->tgt[1][s - (int)npos];
          uint32_t P = ws->P;
          uint32_t lo = 0, hi = P;
          while (lo < hi) {
            uint32_t mid = (lo + hi) >> 1;
            if (ws->T[mid] - mid > e) hi = mid; else lo = mid + 1;
          }
          uint32_t f = e + lo;
          uint32_t i = f >> 6;
          float x = obj[i];
          bc = (double)(fmaxf(x, 0.0f) + log1pf(expf(-fabsf(x))));
        }
        sA[t] = lr; sB[t] = bc;
      }
      __syncthreads();
      for (int off = 128; off > 0; off >>= 1) {
        if (t < off) { sA[t] += sA[t + off]; sB[t] += sB[t + off]; }
        __syncthreads();
      }
      if (t == 0)
        out[0] = (float)(sA[0] * (10.0 / 2500.0) + sB[0] * (1.0 / 256.0));
    }
  }
}

extern "C" void kernel_launch(void* const* d_in, const int* in_sizes, int n_in,
                              void* d_out, int out_size, void* d_ws,
                              size_t ws_size, hipStream_t stream) {
  const float*  reg  = (const float*)d_in[0];
  const float*  obj  = (const float*)d_in[1];
  const float4* pred = (const float4*)d_in[2];
  const float4* tgtb = (const float4*)d_in[3];
  const float4* anch = (const float4*)d_in[4];
  float* out = (float*)d_out;
  WS* ws = (WS*)d_ws;
  (void)in_sizes; (void)n_in; (void)out_size; (void)ws_size;

  hipMemsetAsync(d_ws, 0, ZBYTES, stream);   // ctrl counters + lookback
  k_iou<<<IBLK, 1024, 0, stream>>>(pred, tgtb, ws);
  k_scan_emit<<<CBLK, 256, 0, stream>>>(ws);
  k_histA<<<HBLK, 1024, 0, stream>>>(ws);
  k_redscan<<<HRED + 2, 1024, 0, stream>>>(ws);  // reduce + pos + topK/scanloc1
  for (int m = 1; m < 3; ++m) {
    k_gather<<<CBLK, 1024, 0, stream>>>(ws, m);
    k_selscan<<<MAXSLOT, 1024, 0, stream>>>(ws, m, (m < 2) ? 1 : 2,
                                            reg, obj, tgtb, anch, out);
  }
}